// Round 1
// baseline (1600.530 us; speedup 1.0000x reference)
//
#include <hip/hip_runtime.h>
#include <stdint.h>

#define RTOT 8192
#define BFWD 4      // rows produced per forward block (was 8: 2048 blocks -> 2 waves/SIMD)
#define WFWD 32     // forward warmup steps
#define BBWD 16     // rows per backward block (was 32: 512 blocks -> 2 blocks/CU)
#define WBWD 32     // backward warmup steps
#define LSTR 36     // LDS row stride in floats

typedef unsigned short u16;
typedef __attribute__((ext_vector_type(4))) float f32x4;
typedef __attribute__((ext_vector_type(8))) unsigned short u16x8;

__device__ __forceinline__ float bf2f(u16 u) { return __uint_as_float(((uint32_t)u) << 16); }
__device__ __forceinline__ float rdlane(float v, int l) {
  return __int_as_float(__builtin_amdgcn_readlane(__float_as_int(v), l));
}

// Dual-dtype input loaders. bf==true: bf16 container; bf==false: fp32 container.
__device__ __forceinline__ void load8(const void* p, size_t off, bool bf, float* o) {
  if (bf) {
    u16x8 v = *(const u16x8*)((const u16*)p + off);
    #pragma unroll
    for (int e = 0; e < 8; ++e) o[e] = bf2f(v[e]);
  } else {
    f32x4 a = *(const f32x4*)((const float*)p + off);
    f32x4 b = *(const f32x4*)((const float*)p + off + 4);
    o[0]=a[0]; o[1]=a[1]; o[2]=a[2]; o[3]=a[3];
    o[4]=b[0]; o[5]=b[1]; o[6]=b[2]; o[7]=b[3];
  }
}
__device__ __forceinline__ float load1(const void* p, size_t off, bool bf) {
  return bf ? bf2f(((const u16*)p)[off]) : ((const float*)p)[off];
}

// ======================= DTYPE DETECTOR =======================
__global__ void detect_kernel(const void* Wptr, int* flag) {
  if (threadIdx.x == 0) {
    const u16* w = (const u16*)Wptr;
    int ok = 1;
    const int pi[4] = {0, 0, 1, 2};
    const int pj[4] = {1, 2, 2, 3};
    #pragma unroll
    for (int p = 0; p < 4; ++p)
      ok &= (w[pi[p]*32 + pj[p]] == w[pj[p]*32 + pi[p]]) ? 1 : 0;
    *flag = ok;   // 1 = bf16 container, 0 = fp32 container
  }
}

// ============================ FORWARD ============================
// One wave per block; rows [r0, r0+BFWD) after warmup from max(r0-WFWD,0)
// starting at P=W (Ct=0), u=0.
//   S_r = K0 + H_r - Ct^T Ct   (K0 = W + MtPMt, kept in regs as k0row)
//   L = chol(S); Linv = L^-1 fused into the factorization (right-looking);
//   Ct = Linv*MtP; y = g + u*Ct_prev; u' = Linv*y
// r==0 uses P=x_init_prec exactly (I,W reloaded from global in that rare
// uniform branch); r==RTOT-1 drops MtPMt (S = H + W, W reloaded).
// LDS trimmed to ~9.4KB (setup matrices alias ldsCt/ldsLinv) so 8 blocks/CU
// are resident -> 2 waves/SIMD to hide the chol dependency chains.
__global__ __launch_bounds__(64, 2) void fwd_kernel(
    const void* __restrict__ Hg, const void* __restrict__ Gg,
    const void* __restrict__ Mg, const void* __restrict__ Wg,
    const void* __restrict__ Ig, int s0, const int* __restrict__ flag,
    float* __restrict__ gLinv, float* __restrict__ gCt, float* __restrict__ gU)
{
  __shared__ __align__(16) float ldsCt[32*LSTR];    // setup: M stage, then MtPMt
  __shared__ __align__(16) float ldsLinv[32*LSTR];  // setup: MtP
  __shared__ __align__(16) float ldsU[32];
  __shared__ __align__(16) float ldsY[32];

  const bool bf = (*flag != 0);
  const int lane = threadIdx.x & 63;
  const int il = lane & 31;   // lanes 32-63 duplicate lanes 0-31 (benign dup LDS writes)

  float wrow[32], mrow[32];
  #pragma unroll
  for (int c = 0; c < 4; ++c) {
    float wt[8], mt[8];
    load8(Wg, il*32 + c*8, bf, wt);
    load8(Mg, il*32 + c*8, bf, mt);
    #pragma unroll
    for (int e = 0; e < 8; ++e) {
      wrow[c*8+e] = wt[e]; mrow[c*8+e] = mt[e];
      ldsCt[il*LSTR + c*8+e] = mt[e];          // stage M
    }
  }
  __syncthreads();

  // MtP[m][il] = sum_t M[m][t] * W[t][il]  (W symmetric) -> ldsLinv
  #pragma unroll 4
  for (int m = 0; m < 32; ++m) {
    float acc = 0.0f;
    #pragma unroll
    for (int c = 0; c < 8; ++c) {
      f32x4 q = *(const f32x4*)&ldsCt[m*LSTR + c*4];
      acc = fmaf(q[0], wrow[c*4+0], acc); acc = fmaf(q[1], wrow[c*4+1], acc);
      acc = fmaf(q[2], wrow[c*4+2], acc); acc = fmaf(q[3], wrow[c*4+3], acc);
    }
    ldsLinv[m*LSTR + il] = acc;
  }
  __syncthreads();
  // MtPMt[m][il] = sum_k MtP[m][k] * M[il][k] -> ldsCt (overwrites M)
  #pragma unroll 4
  for (int m = 0; m < 32; ++m) {
    float acc = 0.0f;
    #pragma unroll
    for (int c = 0; c < 8; ++c) {
      f32x4 q = *(const f32x4*)&ldsLinv[m*LSTR + c*4];
      acc = fmaf(q[0], mrow[c*4+0], acc); acc = fmaf(q[1], mrow[c*4+1], acc);
      acc = fmaf(q[2], mrow[c*4+2], acc); acc = fmaf(q[3], mrow[c*4+3], acc);
    }
    ldsCt[m*LSTR + il] = acc;
  }
  __syncthreads();

  float mtpcol[32], k0row[32];
  #pragma unroll
  for (int t = 0; t < 32; ++t) mtpcol[t] = ldsLinv[t*LSTR + il];
  #pragma unroll
  for (int k = 0; k < 32; ++k) k0row[k] = wrow[k] + ldsCt[il*LSTR + k];
  __syncthreads();

  // init running state: Ct = 0, u = 0
  #pragma unroll
  for (int k = 0; k < 32; ++k) ldsCt[il*LSTR + k] = 0.0f;
  if (lane < 32) { ldsU[lane] = 0.0f; ldsY[lane] = 0.0f; }
  __syncthreads();

  const int r0 = s0 + blockIdx.x * BFWD;
  const int rw0 = (r0 >= WFWD) ? (r0 - WFWD) : 0;
  const int rend = r0 + BFWD;

  float hcur[32];
  #pragma unroll
  for (int c = 0; c < 4; ++c) load8(Hg, (size_t)rw0*1024 + il*32 + c*8, bf, &hcur[c*8]);
  float gv = load1(Gg, (size_t)rw0*32 + il, bf);

  for (int r = rw0; r < rend; ++r) {
    // prefetch next H,g
    int rn = (r + 1 < RTOT) ? (r + 1) : r;
    float hnext[32];
    #pragma unroll
    for (int c = 0; c < 4; ++c) load8(Hg, (size_t)rn*1024 + il*32 + c*8, bf, &hnext[c*8]);
    float gvn = load1(Gg, (size_t)rn*32 + il, bf);

    // S row il (rare boundary rows reload I/W from global; uniform branches)
    float row[32];
    if (r == 0) {
      #pragma unroll
      for (int c = 0; c < 4; ++c) {
        float it[8], wt[8];
        load8(Ig, il*32 + c*8, bf, it);
        load8(Wg, il*32 + c*8, bf, wt);
        #pragma unroll
        for (int e = 0; e < 8; ++e)
          row[c*8+e] = hcur[c*8+e] + it[e] + (k0row[c*8+e] - wt[e]);  // H + I + MtPMt
      }
    } else if (r == RTOT - 1) {   // m_s = 0: S = H + W
      #pragma unroll
      for (int c = 0; c < 4; ++c) {
        float wt[8];
        load8(Wg, il*32 + c*8, bf, wt);
        #pragma unroll
        for (int e = 0; e < 8; ++e) row[c*8+e] = hcur[c*8+e] + wt[e];
      }
    } else {
      #pragma unroll
      for (int k = 0; k < 32; ++k) row[k] = hcur[k] + k0row[k];
    }

    // fused: S -= Ct^T Ct  and  y = g + sum_m u[m]*Ct[m][il]  (shares cm read)
    float y = gv;
    #pragma unroll 4
    for (int m = 0; m < 32; ++m) {
      float cm = ldsCt[m*LSTR + il];
      y = fmaf(ldsU[m], cm, y);
      #pragma unroll
      for (int c = 0; c < 8; ++c) {
        f32x4 q = *(const f32x4*)&ldsCt[m*LSTR + c*4];
        row[c*4+0] = fmaf(-cm, q[0], row[c*4+0]);
        row[c*4+1] = fmaf(-cm, q[1], row[c*4+1]);
        row[c*4+2] = fmaf(-cm, q[2], row[c*4+2]);
        row[c*4+3] = fmaf(-cm, q[3], row[c*4+3]);
      }
    }
    ldsY[il] = y;

    // Fused Cholesky + triangular inverse (right-looking).
    // Broadcasts bk = L[k][j] serve BOTH the Schur update and the inverse
    // update -> halves the readlane count and kills the old serial
    // forward-substitution chains. x[i] ends as Linv[i][il].
    float x[32];
    #pragma unroll
    for (int i = 0; i < 32; ++i) x[i] = (il == i) ? 1.0f : 0.0f;
    #pragma unroll
    for (int j = 0; j < 32; ++j) {
      float dj = fmaxf(rdlane(row[j], j), 1e-12f);
      float rs = __builtin_amdgcn_rsqf(dj);
      float cj = row[j] * rs;
      row[j] = cj;
      float xj = x[j] * rs;
      x[j] = xj;
      #pragma unroll
      for (int k = j + 1; k < 32; ++k) {
        float bk = rdlane(row[j], k);       // L[k][j]
        row[k] = fmaf(-cj, bk, row[k]);     // Schur update
        x[k]   = fmaf(-bk, xj, x[k]);       // inverse update
      }
    }

    #pragma unroll
    for (int i = 0; i < 32; ++i) ldsLinv[i*LSTR + il] = x[i];
    __syncthreads();

    // u_new[il] = sum_m Linv[il][m] * y[m]
    float un = 0.0f;
    #pragma unroll
    for (int c = 0; c < 8; ++c) {
      f32x4 q  = *(const f32x4*)&ldsLinv[il*LSTR + c*4];
      f32x4 yv = *(const f32x4*)&ldsY[c*4];
      un = fmaf(q[0], yv[0], un); un = fmaf(q[1], yv[1], un);
      un = fmaf(q[2], yv[2], un); un = fmaf(q[3], yv[3], un);
    }
    ldsU[il] = un;

    // Ct_new[m][il] = sum_t Linv[m][t] * MtP[t][il]
    #pragma unroll 4
    for (int m = 0; m < 32; ++m) {
      float a = 0.0f;
      #pragma unroll
      for (int c = 0; c < 8; ++c) {
        f32x4 q = *(const f32x4*)&ldsLinv[m*LSTR + c*4];
        a = fmaf(q[0], mtpcol[c*4+0], a);
        a = fmaf(q[1], mtpcol[c*4+1], a);
        a = fmaf(q[2], mtpcol[c*4+2], a);
        a = fmaf(q[3], mtpcol[c*4+3], a);
      }
      ldsCt[m*LSTR + il] = a;
    }
    __syncthreads();

    if (r >= r0) {
      size_t ro = (size_t)(r - s0);
      #pragma unroll
      for (int c = 0; c < 4; ++c) {
        int f = lane*16 + c*4;
        int mm = f >> 5, kk = f & 31;
        *(f32x4*)&gLinv[ro*1024 + f] = *(const f32x4*)&ldsLinv[mm*LSTR + kk];
        *(f32x4*)&gCt [ro*1024 + f] = *(const f32x4*)&ldsCt [mm*LSTR + kk];
      }
      if (lane < 32) gU[ro*32 + il] = un;
    }

    #pragma unroll
    for (int c = 0; c < 4; ++c) {
      #pragma unroll
      for (int e = 0; e < 8; ++e) hcur[c*8+e] = hnext[c*8+e];
    }
    gv = gvn;
  }
}

// ============================ BACKWARD ============================
//   X[s][k]   = G[s][k] + sum_m vw[s][m] * B1[k][m]   (B1 = Ct row-major)
//   vw'[s][j] = sum_k X[s][k] * B2[k][j]              (B2 = Linv row-major)
//   out[r][j][:] = vw'[0][:] + vw'[1+j][:]   (fp32 output)
#define MM1(SVAL, GARR)                                                   \
  { int s_ = (SVAL);                                                      \
    float vr[32];                                                         \
    _Pragma("unroll")                                                     \
    for (int c = 0; c < 8; ++c) {                                         \
      f32x4 q = *(const f32x4*)&vw[s_*LSTR + c*4];                        \
      vr[c*4+0]=q[0]; vr[c*4+1]=q[1]; vr[c*4+2]=q[2]; vr[c*4+3]=q[3];     \
    }                                                                     \
    float xr[8];                                                          \
    _Pragma("unroll")                                                     \
    for (int e = 0; e < 8; ++e) {                                         \
      int k_ = oct*8 + e;                                                 \
      float acc = GARR[e];                                                \
      _Pragma("unroll")                                                   \
      for (int c = 0; c < 8; ++c) {                                       \
        f32x4 b = *(const f32x4*)&B1[k_*LSTR + c*4];                      \
        acc = fmaf(vr[c*4+0], b[0], acc);                                 \
        acc = fmaf(vr[c*4+1], b[1], acc);                                 \
        acc = fmaf(vr[c*4+2], b[2], acc);                                 \
        acc = fmaf(vr[c*4+3], b[3], acc);                                 \
      }                                                                   \
      xr[e] = acc;                                                        \
    }                                                                     \
    f32x4 xa = { xr[0], xr[1], xr[2], xr[3] };                            \
    f32x4 xb = { xr[4], xr[5], xr[6], xr[7] };                            \
    *(f32x4*)&Xs[s_*LSTR + oct*8] = xa;                                   \
    *(f32x4*)&Xs[s_*LSTR + oct*8 + 4] = xb;                               \
  }

#define MM2(SVAL)                                                         \
  { int s_ = (SVAL);                                                      \
    float xrr[32];                                                        \
    _Pragma("unroll")                                                     \
    for (int c = 0; c < 8; ++c) {                                         \
      f32x4 q = *(const f32x4*)&Xs[s_*LSTR + c*4];                        \
      xrr[c*4+0]=q[0]; xrr[c*4+1]=q[1]; xrr[c*4+2]=q[2]; xrr[c*4+3]=q[3]; \
    }                                                                     \
    float a0=0,a1=0,a2=0,a3=0,a4=0,a5=0,a6=0,a7=0;                        \
    _Pragma("unroll")                                                     \
    for (int k_ = 0; k_ < 32; ++k_) {                                     \
      f32x4 b = *(const f32x4*)&B2[k_*LSTR + oct*8];                      \
      f32x4 b2 = *(const f32x4*)&B2[k_*LSTR + oct*8 + 4];                 \
      float xk = xrr[k_];                                                 \
      a0 = fmaf(xk, b[0], a0);  a1 = fmaf(xk, b[1], a1);                  \
      a2 = fmaf(xk, b[2], a2);  a3 = fmaf(xk, b2[0], a4);                 \
      a2 = fmaf(xk, b[2], a2);                                            \
    }                                                                     \
  }

#undef MM2
#define MM2(SVAL)                                                         \
  { int s_ = (SVAL);                                                      \
    float xrr[32];                                                        \
    _Pragma("unroll")                                                     \
    for (int c = 0; c < 8; ++c) {                                         \
      f32x4 q = *(const f32x4*)&Xs[s_*LSTR + c*4];                        \
      xrr[c*4+0]=q[0]; xrr[c*4+1]=q[1]; xrr[c*4+2]=q[2]; xrr[c*4+3]=q[3]; \
    }                                                                     \
    float a0=0,a1=0,a2=0,a3=0,a4=0,a5=0,a6=0,a7=0;                        \
    _Pragma("unroll")                                                     \
    for (int k_ = 0; k_ < 32; ++k_) {                                     \
      f32x4 b = *(const f32x4*)&B2[k_*LSTR + oct*8];                      \
      f32x4 b2 = *(const f32x4*)&B2[k_*LSTR + oct*8 + 4];                 \
      float xk = xrr[k_];                                                 \
      a0 = fmaf(xk, b[0], a0);  a1 = fmaf(xk, b[1], a1);                  \
      a2 = fmaf(xk, b[2], a2);  a3 = fmaf(xk, b[3], a3);                  \
      a4 = fmaf(xk, b2[0], a4); a5 = fmaf(xk, b2[1], a5);                 \
      a6 = fmaf(xk, b2[2], a6); a7 = fmaf(xk, b2[3], a7);                 \
    }                                                                     \
    f32x4 va = { a0, a1, a2, a3 };                                        \
    f32x4 vb = { a4, a5, a6, a7 };                                        \
    *(f32x4*)&vw[s_*LSTR + oct*8] = va;                                   \
    *(f32x4*)&vw[s_*LSTR + oct*8 + 4] = vb;                               \
  }

__global__ __launch_bounds__(256, 2) void bwd_kernel(
    const void* __restrict__ Eg,
    const float* __restrict__ gLinv, const float* __restrict__ gCt,
    const float* __restrict__ gU, float* __restrict__ outg, int s0,
    const int* __restrict__ flag)
{
  __shared__ __align__(16) float vw[65*LSTR];
  __shared__ __align__(16) float Xs[65*LSTR];
  __shared__ __align__(16) float B1[32*LSTR];
  __shared__ __align__(16) float B2[32*LSTR];

  const bool bf = (*flag != 0);
  const int t = threadIdx.x;
  const int ss = t >> 2;
  const int oct = t & 3;

  const int r0 = s0 + blockIdx.x * BBWD;
  int re = r0 + BBWD - 1 + WBWD; if (re > RTOT-1) re = RTOT-1;

  for (int i = t; i < 65*LSTR; i += 256) vw[i] = 0.0f;

  // prefetch for r = re
  size_t reo = (size_t)(re - s0);
  f32x4 pB1 = *(const f32x4*)&gCt[reo*1024 + t*4];
  f32x4 pB2 = *(const f32x4*)&gLinv[reo*1024 + t*4];
  float pg0[8], pg1[8];
  if (ss == 0) {
    f32x4 a = *(const f32x4*)&gU[reo*32 + oct*8];
    f32x4 b = *(const f32x4*)&gU[reo*32 + oct*8 + 4];
    pg0[0]=a[0];pg0[1]=a[1];pg0[2]=a[2];pg0[3]=a[3];
    pg0[4]=b[0];pg0[5]=b[1];pg0[6]=b[2];pg0[7]=b[3];
  } else {
    load8(Eg, ((size_t)re*64 + (ss-1))*32 + oct*8, bf, pg0);
  }
  load8(Eg, ((size_t)re*64 + 63)*32 + oct*8, bf, pg1);

  float gc0[8], gc1[8];

  for (int r = re; r >= r0; --r) {
    { // stage prefetched B1/B2/G
      int mm = t >> 3, kk = (t & 7) * 4;
      *(f32x4*)&B1[mm*LSTR + kk] = pB1;
      *(f32x4*)&B2[mm*LSTR + kk] = pB2;
      #pragma unroll
      for (int e = 0; e < 8; ++e) { gc0[e] = pg0[e]; gc1[e] = pg1[e]; }
    }
    __syncthreads();

    if (r > r0) {  // issue prefetch for r-1
      size_t r1o = (size_t)(r - 1 - s0);
      int r1 = r - 1;
      pB1 = *(const f32x4*)&gCt[r1o*1024 + t*4];
      pB2 = *(const f32x4*)&gLinv[r1o*1024 + t*4];
      if (ss == 0) {
        f32x4 a = *(const f32x4*)&gU[r1o*32 + oct*8];
        f32x4 b = *(const f32x4*)&gU[r1o*32 + oct*8 + 4];
        pg0[0]=a[0];pg0[1]=a[1];pg0[2]=a[2];pg0[3]=a[3];
        pg0[4]=b[0];pg0[5]=b[1];pg0[6]=b[2];pg0[7]=b[3];
      } else {
        load8(Eg, ((size_t)r1*64 + (ss-1))*32 + oct*8, bf, pg0);
      }
      load8(Eg, ((size_t)r1*64 + 63)*32 + oct*8, bf, pg1);
    }

    MM1(ss, gc0)
    if (t < 4) MM1(64, gc1)
    __syncthreads();

    MM2(ss)
    if (t < 4) MM2(64)
    __syncthreads();

    if (r < r0 + BBWD) {
      int j = t >> 2, c0 = (t & 3) * 8;
      f32x4 a0 = *(const f32x4*)&vw[(1+j)*LSTR + c0];
      f32x4 a1 = *(const f32x4*)&vw[(1+j)*LSTR + c0 + 4];
      f32x4 b0 = *(const f32x4*)&vw[c0];
      f32x4 b1 = *(const f32x4*)&vw[c0 + 4];
      f32x4 o0, o1;
      o0[0]=a0[0]+b0[0]; o0[1]=a0[1]+b0[1]; o0[2]=a0[2]+b0[2]; o0[3]=a0[3]+b0[3];
      o1[0]=a1[0]+b1[0]; o1[1]=a1[1]+b1[1]; o1[2]=a1[2]+b1[2]; o1[3]=a1[3]+b1[3];
      float* dst = outg + ((size_t)r*64 + j)*32 + c0;
      *(f32x4*)dst = o0;
      *(f32x4*)(dst + 4) = o1;
    }
  }
}

extern "C" void kernel_launch(void* const* d_in, const int* in_sizes, int n_in,
                              void* d_out, int out_size, void* d_ws, size_t ws_size,
                              hipStream_t stream) {
  (void)in_sizes; (void)n_in; (void)out_size;
  const void* H = d_in[0];   // x_hessian_diags [R,32,32] fp32
  const void* G = d_in[1];   // x_grads         [R,1,32]  fp32
  const void* M = d_in[2];   // x_trans_mat     [32,32]   fp32
  const void* W = d_in[3];   // x_trans_prec    [32,32]   fp32
  const void* I = d_in[4];   // x_init_prec     [32,32]   fp32
  const void* E = d_in[5];   // epsx            [R,64,32] fp32
  float* out = (float*)d_out;  // [R,64,32] fp32 (reference output dtype)

  int* flag = (int*)d_ws;                         // dtype flag (first 256 B reserved)
  float* ws0 = (float*)((char*)d_ws + 256);
  size_t avail = (ws_size > 256) ? (ws_size - 256) : 0;

  // Segment R so fp32 Linv/Ct/U (8320 B/row incl. +WBWD extension rows) fit.
  int nseg = 64;
  for (int cand = 1; cand <= 64; cand <<= 1) {
    size_t nrext = (size_t)(RTOT / cand) + WBWD;
    if (nrext * 8320 <= avail) { nseg = cand; break; }
  }
  const int segrows = RTOT / nseg;
  const size_t nrext_max = (size_t)segrows + WBWD;

  float* gLinv = ws0;
  float* gCt  = ws0 + nrext_max * 1024;
  float* gU   = ws0 + nrext_max * 2048;

  detect_kernel<<<1, 64, 0, stream>>>(W, flag);

  for (int s = 0; s < nseg; ++s) {
    int s0 = s * segrows;
    int s1ext = s0 + segrows + WBWD; if (s1ext > RTOT) s1ext = RTOT;
    fwd_kernel<<<(s1ext - s0) / BFWD, 64, 0, stream>>>(H, G, M, W, I, s0, flag, gLinv, gCt, gU);
    bwd_kernel<<<segrows / BBWD, 256, 0, stream>>>(E, gLinv, gCt, gU, out, s0, flag);
  }
}

// Round 2
// 936.876 us; speedup vs baseline: 1.7084x; 1.7084x over previous
//
#include <hip/hip_runtime.h>
#include <stdint.h>

#define RTOT 8192
#define BFWD 4      // rows produced per forward block (2048 blocks -> 2 waves/SIMD)
#define WFWD 32     // forward warmup steps
#define BBWD 32     // rows per backward block (round-0 config: 256 blocks, known-good)
#define WBWD 32     // backward warmup steps
#define LSTR 36     // LDS row stride in floats

typedef unsigned short u16;
typedef __attribute__((ext_vector_type(4))) float f32x4;
typedef __attribute__((ext_vector_type(8))) unsigned short u16x8;

__device__ __forceinline__ float bf2f(u16 u) { return __uint_as_float(((uint32_t)u) << 16); }
__device__ __forceinline__ float rdlane(float v, int l) {
  return __int_as_float(__builtin_amdgcn_readlane(__float_as_int(v), l));
}

// Dual-dtype input loaders. bf==true: bf16 container; bf==false: fp32 container.
__device__ __forceinline__ void load8(const void* p, size_t off, bool bf, float* o) {
  if (bf) {
    u16x8 v = *(const u16x8*)((const u16*)p + off);
    #pragma unroll
    for (int e = 0; e < 8; ++e) o[e] = bf2f(v[e]);
  } else {
    f32x4 a = *(const f32x4*)((const float*)p + off);
    f32x4 b = *(const f32x4*)((const float*)p + off + 4);
    o[0]=a[0]; o[1]=a[1]; o[2]=a[2]; o[3]=a[3];
    o[4]=b[0]; o[5]=b[1]; o[6]=b[2]; o[7]=b[3];
  }
}
__device__ __forceinline__ float load1(const void* p, size_t off, bool bf) {
  return bf ? bf2f(((const u16*)p)[off]) : ((const float*)p)[off];
}

// ======================= DTYPE DETECTOR =======================
__global__ void detect_kernel(const void* Wptr, int* flag) {
  if (threadIdx.x == 0) {
    const u16* w = (const u16*)Wptr;
    int ok = 1;
    const int pi[4] = {0, 0, 1, 2};
    const int pj[4] = {1, 2, 2, 3};
    #pragma unroll
    for (int p = 0; p < 4; ++p)
      ok &= (w[pi[p]*32 + pj[p]] == w[pj[p]*32 + pi[p]]) ? 1 : 0;
    *flag = ok;   // 1 = bf16 container, 0 = fp32 container
  }
}

// ============================ FORWARD ============================
// One wave per block; rows [r0, r0+BFWD) after warmup from max(r0-WFWD,0).
// Half-wave specialization under SHARED instructions:
//   lower lanes (0-31):  v[] = S row il  -> right-looking Cholesky (Schur)
//   upper lanes (32-63): v[] = MtP column il -> right-looking trisolve,
//                        ends as Ct_new[m][il] = (Linv*MtP)[m][il]
// Both use the same broadcasts bk = L[k][j] and the same fma template
//   a = v[j]*rs; v[k] -= a*bk;
// u' = Linv*y is a fused scalar trisolve (3 ops/column, same rs).
// Explicit Linv (stream w, lower lanes) only on output rows (4/36).
// This deletes the 1024-fma Ct_new matmul + 256 ds_read broadcasts and the
// warmup-row inverse maintenance vs the previous version.
__global__ __launch_bounds__(64, 2) void fwd_kernel(
    const void* __restrict__ Hg, const void* __restrict__ Gg,
    const void* __restrict__ Mg, const void* __restrict__ Wg,
    const void* __restrict__ Ig, int s0, const int* __restrict__ flag,
    float* __restrict__ gLinv, float* __restrict__ gCt, float* __restrict__ gU)
{
  __shared__ __align__(16) float ldsCt[32*LSTR];    // setup: M stage, then MtPMt; loop: Ct
  __shared__ __align__(16) float ldsLinv[32*LSTR];  // setup: MtP; loop: Linv (output rows)
  __shared__ float ldsU[32];

  const bool bf = (*flag != 0);
  const int lane = threadIdx.x & 63;
  const int il = lane & 31;
  const bool lo = (lane < 32);

  // ---------------- setup ----------------
  float wrow[32], mrow[32];
  #pragma unroll
  for (int c = 0; c < 4; ++c) {
    float wt[8], mt[8];
    load8(Wg, il*32 + c*8, bf, wt);
    load8(Mg, il*32 + c*8, bf, mt);
    #pragma unroll
    for (int e = 0; e < 8; ++e) {
      wrow[c*8+e] = wt[e]; mrow[c*8+e] = mt[e];
      ldsCt[il*LSTR + c*8+e] = mt[e];          // stage M
    }
  }
  __syncthreads();

  // MtP[m][il] = sum_t M[m][t] * W[t][il]  (W symmetric) -> ldsLinv
  #pragma unroll 4
  for (int m = 0; m < 32; ++m) {
    float acc = 0.0f;
    #pragma unroll
    for (int c = 0; c < 8; ++c) {
      f32x4 q = *(const f32x4*)&ldsCt[m*LSTR + c*4];
      acc = fmaf(q[0], wrow[c*4+0], acc); acc = fmaf(q[1], wrow[c*4+1], acc);
      acc = fmaf(q[2], wrow[c*4+2], acc); acc = fmaf(q[3], wrow[c*4+3], acc);
    }
    ldsLinv[m*LSTR + il] = acc;
  }
  __syncthreads();
  // MtPMt[m][il] = sum_k MtP[m][k] * M[il][k] -> ldsCt (overwrites M)
  #pragma unroll 4
  for (int m = 0; m < 32; ++m) {
    float acc = 0.0f;
    #pragma unroll
    for (int c = 0; c < 8; ++c) {
      f32x4 q = *(const f32x4*)&ldsLinv[m*LSTR + c*4];
      acc = fmaf(q[0], mrow[c*4+0], acc); acc = fmaf(q[1], mrow[c*4+1], acc);
      acc = fmaf(q[2], mrow[c*4+2], acc); acc = fmaf(q[3], mrow[c*4+3], acc);
    }
    ldsCt[m*LSTR + il] = acc;
  }
  __syncthreads();

  float mtpcol[32], k0row[32];
  #pragma unroll
  for (int t = 0; t < 32; ++t) mtpcol[t] = ldsLinv[t*LSTR + il];
  #pragma unroll
  for (int k = 0; k < 32; ++k) k0row[k] = wrow[k] + ldsCt[il*LSTR + k];
  __syncthreads();

  // init running state: Ct = 0, u = 0
  #pragma unroll
  for (int k = 0; k < 32; ++k) ldsCt[il*LSTR + k] = 0.0f;
  if (lo) ldsU[il] = 0.0f;
  __syncthreads();

  const int r0 = s0 + blockIdx.x * BFWD;
  const int rw0 = (r0 >= WFWD) ? (r0 - WFWD) : 0;
  const int rend = r0 + BFWD;

  float hcur[32];
  #pragma unroll
  for (int c = 0; c < 4; ++c) load8(Hg, (size_t)rw0*1024 + il*32 + c*8, bf, &hcur[c*8]);
  float gv = load1(Gg, (size_t)rw0*32 + il, bf);

  for (int r = rw0; r < rend; ++r) {
    // prefetch next H,g
    int rn = (r + 1 < RTOT) ? (r + 1) : r;
    float hnext[32];
    #pragma unroll
    for (int c = 0; c < 4; ++c) load8(Hg, (size_t)rn*1024 + il*32 + c*8, bf, &hnext[c*8]);
    float gvn = load1(Gg, (size_t)rn*32 + il, bf);

    // v init: lower = S base row (K0 + H, boundary variants), upper = MtP col
    float v[32];
    if (r == 0) {
      #pragma unroll
      for (int c = 0; c < 4; ++c) {
        float it[8], wt[8];
        load8(Ig, il*32 + c*8, bf, it);
        load8(Wg, il*32 + c*8, bf, wt);
        #pragma unroll
        for (int e = 0; e < 8; ++e) {
          float t0 = hcur[c*8+e] + it[e] + (k0row[c*8+e] - wt[e]);  // H + I + MtPMt
          v[c*8+e] = lo ? t0 : mtpcol[c*8+e];
        }
      }
    } else if (r == RTOT - 1) {   // m_s = 0: S = H + W
      #pragma unroll
      for (int c = 0; c < 4; ++c) {
        float wt[8];
        load8(Wg, il*32 + c*8, bf, wt);
        #pragma unroll
        for (int e = 0; e < 8; ++e) {
          float t0 = hcur[c*8+e] + wt[e];
          v[c*8+e] = lo ? t0 : mtpcol[c*8+e];
        }
      }
    } else {
      #pragma unroll
      for (int k = 0; k < 32; ++k) {
        float t0 = hcur[k] + k0row[k];
        v[k] = lo ? t0 : mtpcol[k];
      }
    }

    // fused: S -= Ct^T Ct (lower only; cm forced 0 in upper so upper keeps MtP)
    // and   y = g + sum_m u[m]*Ct[m][il]
    float y = gv;
    #pragma unroll 4
    for (int m = 0; m < 32; ++m) {
      float cm = ldsCt[m*LSTR + il];
      cm = lo ? cm : 0.0f;
      y = fmaf(ldsU[m], cm, y);
      #pragma unroll
      for (int c = 0; c < 8; ++c) {
        f32x4 q = *(const f32x4*)&ldsCt[m*LSTR + c*4];
        v[c*4+0] = fmaf(-cm, q[0], v[c*4+0]);
        v[c*4+1] = fmaf(-cm, q[1], v[c*4+1]);
        v[c*4+2] = fmaf(-cm, q[2], v[c*4+2]);
        v[c*4+3] = fmaf(-cm, q[3], v[c*4+3]);
      }
    }

    float un = 0.0f;
    float yr = y;
    if (r < r0) {
      // warmup: chol (lower) + Ct trisolve (upper) + u trisolve (scalar chain)
      #pragma unroll
      for (int j = 0; j < 32; ++j) {
        float dj = fmaxf(rdlane(v[j], j), 1e-12f);
        float rs = __builtin_amdgcn_rsqf(dj);
        float a = v[j] * rs;            // lower: L[il][j]; upper: Ct_new[j][il]
        v[j] = a;
        float uj = rdlane(yr, j) * rs;  // u'[j]  (1/L[jj] == rs)
        yr = fmaf(-a, uj, yr);
        if (il == j) un = uj;
        #pragma unroll
        for (int k = j + 1; k < 32; ++k) {
          float bk = rdlane(v[j], k);   // L[k][j]
          v[k] = fmaf(-a, bk, v[k]);
        }
      }
    } else {
      // output row: also maintain explicit Linv (stream w, lower lanes)
      float w[32];
      #pragma unroll
      for (int i = 0; i < 32; ++i) w[i] = (lo && il == i) ? 1.0f : 0.0f;
      #pragma unroll
      for (int j = 0; j < 32; ++j) {
        float dj = fmaxf(rdlane(v[j], j), 1e-12f);
        float rs = __builtin_amdgcn_rsqf(dj);
        float a = v[j] * rs;
        v[j] = a;
        float b = w[j] * rs;            // lower: Linv[j][il]
        w[j] = b;
        float uj = rdlane(yr, j) * rs;
        yr = fmaf(-a, uj, yr);
        if (il == j) un = uj;
        #pragma unroll
        for (int k = j + 1; k < 32; ++k) {
          float bk = rdlane(v[j], k);
          v[k] = fmaf(-a, bk, v[k]);
          w[k] = fmaf(-b, bk, w[k]);
        }
      }
      if (lo) {
        #pragma unroll
        for (int i = 0; i < 32; ++i) ldsLinv[i*LSTR + il] = w[i];
      }
    }

    // commit new Ct (upper lanes) and u (lower lanes); single wave -> DS ops
    // are in-order, no barrier needed between iterations.
    if (!lo) {
      #pragma unroll
      for (int m = 0; m < 32; ++m) ldsCt[m*LSTR + il] = v[m];
    } else {
      ldsU[il] = un;
    }

    if (r >= r0) {
      __syncthreads();
      size_t ro = (size_t)(r - s0);
      #pragma unroll
      for (int c = 0; c < 4; ++c) {
        int f = lane*16 + c*4;
        int mm = f >> 5, kk = f & 31;
        *(f32x4*)&gLinv[ro*1024 + f] = *(const f32x4*)&ldsLinv[mm*LSTR + kk];
        *(f32x4*)&gCt [ro*1024 + f] = *(const f32x4*)&ldsCt [mm*LSTR + kk];
      }
      if (lo) gU[ro*32 + il] = un;
    }

    #pragma unroll
    for (int c = 0; c < 4; ++c) {
      #pragma unroll
      for (int e = 0; e < 8; ++e) hcur[c*8+e] = hnext[c*8+e];
    }
    gv = gvn;
  }
}

// ============================ BACKWARD ============================
// (exact round-0 configuration: BBWD=32, launch_bounds(256,1) — known 365 us)
//   X[s][k]   = G[s][k] + sum_m vw[s][m] * B1[k][m]   (B1 = Ct row-major)
//   vw'[s][j] = sum_k X[s][k] * B2[k][j]              (B2 = Linv row-major)
//   out[r][j][:] = vw'[0][:] + vw'[1+j][:]   (fp32 output)
#define MM1(SVAL, GARR)                                                   \
  { int s_ = (SVAL);                                                      \
    float vr[32];                                                         \
    _Pragma("unroll")                                                     \
    for (int c = 0; c < 8; ++c) {                                         \
      f32x4 q = *(const f32x4*)&vw[s_*LSTR + c*4];                        \
      vr[c*4+0]=q[0]; vr[c*4+1]=q[1]; vr[c*4+2]=q[2]; vr[c*4+3]=q[3];     \
    }                                                                     \
    float xr[8];                                                          \
    _Pragma("unroll")                                                     \
    for (int e = 0; e < 8; ++e) {                                         \
      int k_ = oct*8 + e;                                                 \
      float acc = GARR[e];                                                \
      _Pragma("unroll")                                                   \
      for (int c = 0; c < 8; ++c) {                                       \
        f32x4 b = *(const f32x4*)&B1[k_*LSTR + c*4];                      \
        acc = fmaf(vr[c*4+0], b[0], acc);                                 \
        acc = fmaf(vr[c*4+1], b[1], acc);                                 \
        acc = fmaf(vr[c*4+2], b[2], acc);                                 \
        acc = fmaf(vr[c*4+3], b[3], acc);                                 \
      }                                                                   \
      xr[e] = acc;                                                       \
    }                                                                     \
    f32x4 xa = { xr[0], xr[1], xr[2], xr[3] };                            \
    f32x4 xb = { xr[4], xr[5], xr[6], xr[7] };                            \
    *(f32x4*)&Xs[s_*LSTR + oct*8] = xa;                                   \
    *(f32x4*)&Xs[s_*LSTR + oct*8 + 4] = xb;                               \
  }

#define MM2(SVAL)                                                         \
  { int s_ = (SVAL);                                                      \
    float xrr[32];                                                        \
    _Pragma("unroll")                                                     \
    for (int c = 0; c < 8; ++c) {                                         \
      f32x4 q = *(const f32x4*)&Xs[s_*LSTR + c*4];                        \
      xrr[c*4+0]=q[0]; xrr[c*4+1]=q[1]; xrr[c*4+2]=q[2]; xrr[c*4+3]=q[3]; \
    }                                                                     \
    float a0=0,a1=0,a2=0,a3=0,a4=0,a5=0,a6=0,a7=0;                        \
    _Pragma("unroll")                                                     \
    for (int k_ = 0; k_ < 32; ++k_) {                                     \
      f32x4 b = *(const f32x4*)&B2[k_*LSTR + oct*8];                      \
      f32x4 b2 = *(const f32x4*)&B2[k_*LSTR + oct*8 + 4];                 \
      float xk = xrr[k_];                                                 \
      a0 = fmaf(xk, b[0], a0);  a1 = fmaf(xk, b[1], a1);                  \
      a2 = fmaf(xk, b[2], a2);  a3 = fmaf(xk, b[3], a3);                  \
      a4 = fmaf(xk, b2[0], a4); a5 = fmaf(xk, b2[1], a5);                 \
      a6 = fmaf(xk, b2[2], a6); a7 = fmaf(xk, b2[3], a7);                 \
    }                                                                     \
    f32x4 va = { a0, a1, a2, a3 };                                        \
    f32x4 vb = { a4, a5, a6, a7 };                                        \
    *(f32x4*)&vw[s_*LSTR + oct*8] = va;                                   \
    *(f32x4*)&vw[s_*LSTR + oct*8 + 4] = vb;                               \
  }

__global__ __launch_bounds__(256, 1) void bwd_kernel(
    const void* __restrict__ Eg,
    const float* __restrict__ gLinv, const float* __restrict__ gCt,
    const float* __restrict__ gU, float* __restrict__ outg, int s0,
    const int* __restrict__ flag)
{
  __shared__ __align__(16) float vw[65*LSTR];
  __shared__ __align__(16) float Xs[65*LSTR];
  __shared__ __align__(16) float B1[32*LSTR];
  __shared__ __align__(16) float B2[32*LSTR];

  const bool bf = (*flag != 0);
  const int t = threadIdx.x;
  const int ss = t >> 2;
  const int oct = t & 3;

  const int r0 = s0 + blockIdx.x * BBWD;
  int re = r0 + BBWD - 1 + WBWD; if (re > RTOT-1) re = RTOT-1;

  for (int i = t; i < 65*LSTR; i += 256) vw[i] = 0.0f;

  // prefetch for r = re
  size_t reo = (size_t)(re - s0);
  f32x4 pB1 = *(const f32x4*)&gCt[reo*1024 + t*4];
  f32x4 pB2 = *(const f32x4*)&gLinv[reo*1024 + t*4];
  float pg0[8], pg1[8];
  if (ss == 0) {
    f32x4 a = *(const f32x4*)&gU[reo*32 + oct*8];
    f32x4 b = *(const f32x4*)&gU[reo*32 + oct*8 + 4];
    pg0[0]=a[0];pg0[1]=a[1];pg0[2]=a[2];pg0[3]=a[3];
    pg0[4]=b[0];pg0[5]=b[1];pg0[6]=b[2];pg0[7]=b[3];
  } else {
    load8(Eg, ((size_t)re*64 + (ss-1))*32 + oct*8, bf, pg0);
  }
  load8(Eg, ((size_t)re*64 + 63)*32 + oct*8, bf, pg1);

  float gc0[8], gc1[8];

  for (int r = re; r >= r0; --r) {
    { // stage prefetched B1/B2/G
      int mm = t >> 3, kk = (t & 7) * 4;
      *(f32x4*)&B1[mm*LSTR + kk] = pB1;
      *(f32x4*)&B2[mm*LSTR + kk] = pB2;
      #pragma unroll
      for (int e = 0; e < 8; ++e) { gc0[e] = pg0[e]; gc1[e] = pg1[e]; }
    }
    __syncthreads();

    if (r > r0) {  // issue prefetch for r-1
      size_t r1o = (size_t)(r - 1 - s0);
      int r1 = r - 1;
      pB1 = *(const f32x4*)&gCt[r1o*1024 + t*4];
      pB2 = *(const f32x4*)&gLinv[r1o*1024 + t*4];
      if (ss == 0) {
        f32x4 a = *(const f32x4*)&gU[r1o*32 + oct*8];
        f32x4 b = *(const f32x4*)&gU[r1o*32 + oct*8 + 4];
        pg0[0]=a[0];pg0[1]=a[1];pg0[2]=a[2];pg0[3]=a[3];
        pg0[4]=b[0];pg0[5]=b[1];pg0[6]=b[2];pg0[7]=b[3];
      } else {
        load8(Eg, ((size_t)r1*64 + (ss-1))*32 + oct*8, bf, pg0);
      }
      load8(Eg, ((size_t)r1*64 + 63)*32 + oct*8, bf, pg1);
    }

    MM1(ss, gc0)
    if (t < 4) MM1(64, gc1)
    __syncthreads();

    MM2(ss)
    if (t < 4) MM2(64)
    __syncthreads();

    if (r < r0 + BBWD) {
      int j = t >> 2, c0 = (t & 3) * 8;
      f32x4 a0 = *(const f32x4*)&vw[(1+j)*LSTR + c0];
      f32x4 a1 = *(const f32x4*)&vw[(1+j)*LSTR + c0 + 4];
      f32x4 b0 = *(const f32x4*)&vw[c0];
      f32x4 b1 = *(const f32x4*)&vw[c0 + 4];
      f32x4 o0, o1;
      o0[0]=a0[0]+b0[0]; o0[1]=a0[1]+b0[1]; o0[2]=a0[2]+b0[2]; o0[3]=a0[3]+b0[3];
      o1[0]=a1[0]+b1[0]; o1[1]=a1[1]+b1[1]; o1[2]=a1[2]+b1[2]; o1[3]=a1[3]+b1[3];
      float* dst = outg + ((size_t)r*64 + j)*32 + c0;
      *(f32x4*)dst = o0;
      *(f32x4*)(dst + 4) = o1;
    }
  }
}

extern "C" void kernel_launch(void* const* d_in, const int* in_sizes, int n_in,
                              void* d_out, int out_size, void* d_ws, size_t ws_size,
                              hipStream_t stream) {
  (void)in_sizes; (void)n_in; (void)out_size;
  const void* H = d_in[0];   // x_hessian_diags [R,32,32] fp32
  const void* G = d_in[1];   // x_grads         [R,1,32]  fp32
  const void* M = d_in[2];   // x_trans_mat     [32,32]   fp32
  const void* W = d_in[3];   // x_trans_prec    [32,32]   fp32
  const void* I = d_in[4];   // x_init_prec     [32,32]   fp32
  const void* E = d_in[5];   // epsx            [R,64,32] fp32
  float* out = (float*)d_out;  // [R,64,32] fp32 (reference output dtype)

  int* flag = (int*)d_ws;                         // dtype flag (first 256 B reserved)
  float* ws0 = (float*)((char*)d_ws + 256);
  size_t avail = (ws_size > 256) ? (ws_size - 256) : 0;

  // Segment R so fp32 Linv/Ct/U (8320 B/row incl. +WBWD extension rows) fit.
  int nseg = 64;
  for (int cand = 1; cand <= 64; cand <<= 1) {
    size_t nrext = (size_t)(RTOT / cand) + WBWD;
    if (nrext * 8320 <= avail) { nseg = cand; break; }
  }
  const int segrows = RTOT / nseg;
  const size_t nrext_max = (size_t)segrows + WBWD;

  float* gLinv = ws0;
  float* gCt  = ws0 + nrext_max * 1024;
  float* gU   = ws0 + nrext_max * 2048;

  detect_kernel<<<1, 64, 0, stream>>>(W, flag);

  for (int s = 0; s < nseg; ++s) {
    int s0 = s * segrows;
    int s1ext = s0 + segrows + WBWD; if (s1ext > RTOT) s1ext = RTOT;
    fwd_kernel<<<(s1ext - s0) / BFWD, 64, 0, stream>>>(H, G, M, W, I, s0, flag, gLinv, gCt, gU);
    bwd_kernel<<<segrows / BBWD, 256, 0, stream>>>(E, gLinv, gCt, gU, out, s0, flag);
  }
}

// Round 3
// 801.503 us; speedup vs baseline: 1.9969x; 1.1689x over previous
//
#include <hip/hip_runtime.h>
#include <stdint.h>

#define RTOT 8192
#define BFWD 4      // rows produced per forward block (2048 blocks -> 2 waves/SIMD)
#define WFWD 24     // forward warmup steps (32->24: error invisible at bf16 floor)
#define BBWD 32     // rows per backward block (256 blocks; 2 blocks/CU saturates LDS pipe)
#define WBWD 24     // backward warmup steps (32->24)
#define LSTR 36     // LDS row stride in floats

typedef unsigned short u16;
typedef __attribute__((ext_vector_type(4))) float f32x4;
typedef __attribute__((ext_vector_type(8))) unsigned short u16x8;

__device__ __forceinline__ float bf2f(u16 u) { return __uint_as_float(((uint32_t)u) << 16); }
__device__ __forceinline__ float rdlane(float v, int l) {
  return __int_as_float(__builtin_amdgcn_readlane(__float_as_int(v), l));
}

// Dual-dtype input loaders. bf==true: bf16 container; bf==false: fp32 container.
__device__ __forceinline__ void load8(const void* p, size_t off, bool bf, float* o) {
  if (bf) {
    u16x8 v = *(const u16x8*)((const u16*)p + off);
    #pragma unroll
    for (int e = 0; e < 8; ++e) o[e] = bf2f(v[e]);
  } else {
    f32x4 a = *(const f32x4*)((const float*)p + off);
    f32x4 b = *(const f32x4*)((const float*)p + off + 4);
    o[0]=a[0]; o[1]=a[1]; o[2]=a[2]; o[3]=a[3];
    o[4]=b[0]; o[5]=b[1]; o[6]=b[2]; o[7]=b[3];
  }
}
__device__ __forceinline__ float load1(const void* p, size_t off, bool bf) {
  return bf ? bf2f(((const u16*)p)[off]) : ((const float*)p)[off];
}

// ======================= DTYPE DETECTOR =======================
__global__ void detect_kernel(const void* Wptr, int* flag) {
  if (threadIdx.x == 0) {
    const u16* w = (const u16*)Wptr;
    int ok = 1;
    const int pi[4] = {0, 0, 1, 2};
    const int pj[4] = {1, 2, 2, 3};
    #pragma unroll
    for (int p = 0; p < 4; ++p)
      ok &= (w[pi[p]*32 + pj[p]] == w[pj[p]*32 + pi[p]]) ? 1 : 0;
    *flag = ok;   // 1 = bf16 container, 0 = fp32 container
  }
}

// ============================ FORWARD ============================
// One wave per block; rows [r0, r0+BFWD) after warmup from max(r0-WFWD,0).
// Half-wave specialization under SHARED instructions:
//   lower lanes (0-31):  v[] = S row il  -> right-looking Cholesky (Schur)
//   upper lanes (32-63): v[] = MtP column il -> right-looking trisolve,
//                        ends as Ct_new[m][il] = (Linv*MtP)[m][il]
// Both use the same broadcasts bk = L[k][j] and the same fma template
//   a = v[j]*rs; v[k] -= a*bk;
// u' = Linv*y is a fused scalar trisolve (3 ops/column, same rs).
// Explicit Linv (stream w, lower lanes) only on output rows.
__global__ __launch_bounds__(64, 2) void fwd_kernel(
    const void* __restrict__ Hg, const void* __restrict__ Gg,
    const void* __restrict__ Mg, const void* __restrict__ Wg,
    const void* __restrict__ Ig, int s0, const int* __restrict__ flag,
    float* __restrict__ gLinv, float* __restrict__ gCt, float* __restrict__ gU)
{
  __shared__ __align__(16) float ldsCt[32*LSTR];    // setup: M stage, then MtPMt; loop: Ct
  __shared__ __align__(16) float ldsLinv[32*LSTR];  // setup: MtP; loop: Linv (output rows)
  __shared__ float ldsU[32];

  const bool bf = (*flag != 0);
  const int lane = threadIdx.x & 63;
  const int il = lane & 31;
  const bool lo = (lane < 32);

  // ---------------- setup ----------------
  float wrow[32], mrow[32];
  #pragma unroll
  for (int c = 0; c < 4; ++c) {
    float wt[8], mt[8];
    load8(Wg, il*32 + c*8, bf, wt);
    load8(Mg, il*32 + c*8, bf, mt);
    #pragma unroll
    for (int e = 0; e < 8; ++e) {
      wrow[c*8+e] = wt[e]; mrow[c*8+e] = mt[e];
      ldsCt[il*LSTR + c*8+e] = mt[e];          // stage M
    }
  }
  __syncthreads();

  // MtP[m][il] = sum_t M[m][t] * W[t][il]  (W symmetric) -> ldsLinv
  #pragma unroll 4
  for (int m = 0; m < 32; ++m) {
    float acc = 0.0f;
    #pragma unroll
    for (int c = 0; c < 8; ++c) {
      f32x4 q = *(const f32x4*)&ldsCt[m*LSTR + c*4];
      acc = fmaf(q[0], wrow[c*4+0], acc); acc = fmaf(q[1], wrow[c*4+1], acc);
      acc = fmaf(q[2], wrow[c*4+2], acc); acc = fmaf(q[3], wrow[c*4+3], acc);
    }
    ldsLinv[m*LSTR + il] = acc;
  }
  __syncthreads();
  // MtPMt[m][il] = sum_k MtP[m][k] * M[il][k] -> ldsCt (overwrites M)
  #pragma unroll 4
  for (int m = 0; m < 32; ++m) {
    float acc = 0.0f;
    #pragma unroll
    for (int c = 0; c < 8; ++c) {
      f32x4 q = *(const f32x4*)&ldsLinv[m*LSTR + c*4];
      acc = fmaf(q[0], mrow[c*4+0], acc); acc = fmaf(q[1], mrow[c*4+1], acc);
      acc = fmaf(q[2], mrow[c*4+2], acc); acc = fmaf(q[3], mrow[c*4+3], acc);
    }
    ldsCt[m*LSTR + il] = acc;
  }
  __syncthreads();

  float mtpcol[32], k0row[32];
  #pragma unroll
  for (int t = 0; t < 32; ++t) mtpcol[t] = ldsLinv[t*LSTR + il];
  #pragma unroll
  for (int k = 0; k < 32; ++k) k0row[k] = wrow[k] + ldsCt[il*LSTR + k];
  __syncthreads();

  // init running state: Ct = 0, u = 0
  #pragma unroll
  for (int k = 0; k < 32; ++k) ldsCt[il*LSTR + k] = 0.0f;
  if (lo) ldsU[il] = 0.0f;
  __syncthreads();

  const int r0 = s0 + blockIdx.x * BFWD;
  const int rw0 = (r0 >= WFWD) ? (r0 - WFWD) : 0;
  const int rend = r0 + BFWD;

  float hcur[32];
  #pragma unroll
  for (int c = 0; c < 4; ++c) load8(Hg, (size_t)rw0*1024 + il*32 + c*8, bf, &hcur[c*8]);
  float gv = load1(Gg, (size_t)rw0*32 + il, bf);

  for (int r = rw0; r < rend; ++r) {
    // prefetch next H,g
    int rn = (r + 1 < RTOT) ? (r + 1) : r;
    float hnext[32];
    #pragma unroll
    for (int c = 0; c < 4; ++c) load8(Hg, (size_t)rn*1024 + il*32 + c*8, bf, &hnext[c*8]);
    float gvn = load1(Gg, (size_t)rn*32 + il, bf);

    // v init: lower = S base row (K0 + H, boundary variants), upper = MtP col
    float v[32];
    if (r == 0) {
      #pragma unroll
      for (int c = 0; c < 4; ++c) {
        float it[8], wt[8];
        load8(Ig, il*32 + c*8, bf, it);
        load8(Wg, il*32 + c*8, bf, wt);
        #pragma unroll
        for (int e = 0; e < 8; ++e) {
          float t0 = hcur[c*8+e] + it[e] + (k0row[c*8+e] - wt[e]);  // H + I + MtPMt
          v[c*8+e] = lo ? t0 : mtpcol[c*8+e];
        }
      }
    } else if (r == RTOT - 1) {   // m_s = 0: S = H + W
      #pragma unroll
      for (int c = 0; c < 4; ++c) {
        float wt[8];
        load8(Wg, il*32 + c*8, bf, wt);
        #pragma unroll
        for (int e = 0; e < 8; ++e) {
          float t0 = hcur[c*8+e] + wt[e];
          v[c*8+e] = lo ? t0 : mtpcol[c*8+e];
        }
      }
    } else {
      #pragma unroll
      for (int k = 0; k < 32; ++k) {
        float t0 = hcur[k] + k0row[k];
        v[k] = lo ? t0 : mtpcol[k];
      }
    }

    // fused: S -= Ct^T Ct (lower only; cm forced 0 in upper so upper keeps MtP)
    // and   y = g + sum_m u[m]*Ct[m][il]
    float y = gv;
    #pragma unroll 4
    for (int m = 0; m < 32; ++m) {
      float cm = ldsCt[m*LSTR + il];
      cm = lo ? cm : 0.0f;
      y = fmaf(ldsU[m], cm, y);
      #pragma unroll
      for (int c = 0; c < 8; ++c) {
        f32x4 q = *(const f32x4*)&ldsCt[m*LSTR + c*4];
        v[c*4+0] = fmaf(-cm, q[0], v[c*4+0]);
        v[c*4+1] = fmaf(-cm, q[1], v[c*4+1]);
        v[c*4+2] = fmaf(-cm, q[2], v[c*4+2]);
        v[c*4+3] = fmaf(-cm, q[3], v[c*4+3]);
      }
    }

    float un = 0.0f;
    float yr = y;
    if (r < r0) {
      // warmup: chol (lower) + Ct trisolve (upper) + u trisolve (scalar chain)
      #pragma unroll
      for (int j = 0; j < 32; ++j) {
        float dj = fmaxf(rdlane(v[j], j), 1e-12f);
        float rs = __builtin_amdgcn_rsqf(dj);
        float a = v[j] * rs;            // lower: L[il][j]; upper: Ct_new[j][il]
        v[j] = a;
        float uj = rdlane(yr, j) * rs;  // u'[j]  (1/L[jj] == rs)
        yr = fmaf(-a, uj, yr);
        if (il == j) un = uj;
        #pragma unroll
        for (int k = j + 1; k < 32; ++k) {
          float bk = rdlane(v[j], k);   // L[k][j]
          v[k] = fmaf(-a, bk, v[k]);
        }
      }
    } else {
      // output row: also maintain explicit Linv (stream w, lower lanes)
      float w[32];
      #pragma unroll
      for (int i = 0; i < 32; ++i) w[i] = (lo && il == i) ? 1.0f : 0.0f;
      #pragma unroll
      for (int j = 0; j < 32; ++j) {
        float dj = fmaxf(rdlane(v[j], j), 1e-12f);
        float rs = __builtin_amdgcn_rsqf(dj);
        float a = v[j] * rs;
        v[j] = a;
        float b = w[j] * rs;            // lower: Linv[j][il]
        w[j] = b;
        float uj = rdlane(yr, j) * rs;
        yr = fmaf(-a, uj, yr);
        if (il == j) un = uj;
        #pragma unroll
        for (int k = j + 1; k < 32; ++k) {
          float bk = rdlane(v[j], k);
          v[k] = fmaf(-a, bk, v[k]);
          w[k] = fmaf(-b, bk, w[k]);
        }
      }
      if (lo) {
        #pragma unroll
        for (int i = 0; i < 32; ++i) ldsLinv[i*LSTR + il] = w[i];
      }
    }

    // commit new Ct (upper lanes) and u (lower lanes); single wave -> DS ops
    // are in-order, no barrier needed between iterations.
    if (!lo) {
      #pragma unroll
      for (int m = 0; m < 32; ++m) ldsCt[m*LSTR + il] = v[m];
    } else {
      ldsU[il] = un;
    }

    if (r >= r0) {
      __syncthreads();
      size_t ro = (size_t)(r - s0);
      #pragma unroll
      for (int c = 0; c < 4; ++c) {
        int f = lane*16 + c*4;
        int mm = f >> 5, kk = f & 31;
        *(f32x4*)&gLinv[ro*1024 + f] = *(const f32x4*)&ldsLinv[mm*LSTR + kk];
        *(f32x4*)&gCt [ro*1024 + f] = *(const f32x4*)&ldsCt [mm*LSTR + kk];
      }
      if (lo) gU[ro*32 + il] = un;
    }

    #pragma unroll
    for (int c = 0; c < 4; ++c) {
      #pragma unroll
      for (int e = 0; e < 8; ++e) hcur[c*8+e] = hnext[c*8+e];
    }
    gv = gvn;
  }
}

// ============================ BACKWARD ============================
// (round-0 configuration: BBWD=32, launch_bounds(256,1) — known-good)
//   X[s][k]   = G[s][k] + sum_m vw[s][m] * B1[k][m]   (B1 = Ct row-major)
//   vw'[s][j] = sum_k X[s][k] * B2[k][j]              (B2 = Linv row-major)
//   out[r][j][:] = vw'[0][:] + vw'[1+j][:]   (fp32 output)
#define MM1(SVAL, GARR)                                                   \
  { int s_ = (SVAL);                                                      \
    float vr[32];                                                         \
    _Pragma("unroll")                                                     \
    for (int c = 0; c < 8; ++c) {                                         \
      f32x4 q = *(const f32x4*)&vw[s_*LSTR + c*4];                        \
      vr[c*4+0]=q[0]; vr[c*4+1]=q[1]; vr[c*4+2]=q[2]; vr[c*4+3]=q[3];     \
    }                                                                     \
    float xr[8];                                                          \
    _Pragma("unroll")                                                     \
    for (int e = 0; e < 8; ++e) {                                         \
      int k_ = oct*8 + e;                                                 \
      float acc = GARR[e];                                                \
      _Pragma("unroll")                                                   \
      for (int c = 0; c < 8; ++c) {                                       \
        f32x4 b = *(const f32x4*)&B1[k_*LSTR + c*4];                      \
        acc = fmaf(vr[c*4+0], b[0], acc);                                 \
        acc = fmaf(vr[c*4+1], b[1], acc);                                 \
        acc = fmaf(vr[c*4+2], b[2], acc);                                 \
        acc = fmaf(vr[c*4+3], b[3], acc);                                 \
      }                                                                   \
      xr[e] = acc;                                                       \
    }                                                                     \
    f32x4 xa = { xr[0], xr[1], xr[2], xr[3] };                            \
    f32x4 xb = { xr[4], xr[5], xr[6], xr[7] };                            \
    *(f32x4*)&Xs[s_*LSTR + oct*8] = xa;                                   \
    *(f32x4*)&Xs[s_*LSTR + oct*8 + 4] = xb;                               \
  }

#define MM2(SVAL)                                                         \
  { int s_ = (SVAL);                                                      \
    float xrr[32];                                                        \
    _Pragma("unroll")                                                     \
    for (int c = 0; c < 8; ++c) {                                         \
      f32x4 q = *(const f32x4*)&Xs[s_*LSTR + c*4];                        \
      xrr[c*4+0]=q[0]; xrr[c*4+1]=q[1]; xrr[c*4+2]=q[2]; xrr[c*4+3]=q[3]; \
    }                                                                     \
    float a0=0,a1=0,a2=0,a3=0,a4=0,a5=0,a6=0,a7=0;                        \
    _Pragma("unroll")                                                     \
    for (int k_ = 0; k_ < 32; ++k_) {                                     \
      f32x4 b = *(const f32x4*)&B2[k_*LSTR + oct*8];                      \
      f32x4 b2 = *(const f32x4*)&B2[k_*LSTR + oct*8 + 4];                 \
      float xk = xrr[k_];                                                 \
      a0 = fmaf(xk, b[0], a0);  a1 = fmaf(xk, b[1], a1);                  \
      a2 = fmaf(xk, b[2], a2);  a3 = fmaf(xk, b[3], a3);                  \
      a4 = fmaf(xk, b2[0], a4); a5 = fmaf(xk, b2[1], a5);                 \
      a6 = fmaf(xk, b2[2], a6); a7 = fmaf(xk, b2[3], a7);                 \
    }                                                                     \
    f32x4 va = { a0, a1, a2, a3 };                                        \
    f32x4 vb = { a4, a5, a6, a7 };                                        \
    *(f32x4*)&vw[s_*LSTR + oct*8] = va;                                   \
    *(f32x4*)&vw[s_*LSTR + oct*8 + 4] = vb;                               \
  }

__global__ __launch_bounds__(256, 1) void bwd_kernel(
    const void* __restrict__ Eg,
    const float* __restrict__ gLinv, const float* __restrict__ gCt,
    const float* __restrict__ gU, float* __restrict__ outg, int s0,
    const int* __restrict__ flag)
{
  __shared__ __align__(16) float vw[65*LSTR];
  __shared__ __align__(16) float Xs[65*LSTR];
  __shared__ __align__(16) float B1[32*LSTR];
  __shared__ __align__(16) float B2[32*LSTR];

  const bool bf = (*flag != 0);
  const int t = threadIdx.x;
  const int ss = t >> 2;
  const int oct = t & 3;

  const int r0 = s0 + blockIdx.x * BBWD;
  int re = r0 + BBWD - 1 + WBWD; if (re > RTOT-1) re = RTOT-1;

  for (int i = t; i < 65*LSTR; i += 256) vw[i] = 0.0f;

  // prefetch for r = re
  size_t reo = (size_t)(re - s0);
  f32x4 pB1 = *(const f32x4*)&gCt[reo*1024 + t*4];
  f32x4 pB2 = *(const f32x4*)&gLinv[reo*1024 + t*4];
  float pg0[8], pg1[8];
  if (ss == 0) {
    f32x4 a = *(const f32x4*)&gU[reo*32 + oct*8];
    f32x4 b = *(const f32x4*)&gU[reo*32 + oct*8 + 4];
    pg0[0]=a[0];pg0[1]=a[1];pg0[2]=a[2];pg0[3]=a[3];
    pg0[4]=b[0];pg0[5]=b[1];pg0[6]=b[2];pg0[7]=b[3];
  } else {
    load8(Eg, ((size_t)re*64 + (ss-1))*32 + oct*8, bf, pg0);
  }
  load8(Eg, ((size_t)re*64 + 63)*32 + oct*8, bf, pg1);

  float gc0[8], gc1[8];

  for (int r = re; r >= r0; --r) {
    { // stage prefetched B1/B2/G
      int mm = t >> 3, kk = (t & 7) * 4;
      *(f32x4*)&B1[mm*LSTR + kk] = pB1;
      *(f32x4*)&B2[mm*LSTR + kk] = pB2;
      #pragma unroll
      for (int e = 0; e < 8; ++e) { gc0[e] = pg0[e]; gc1[e] = pg1[e]; }
    }
    __syncthreads();

    if (r > r0) {  // issue prefetch for r-1
      size_t r1o = (size_t)(r - 1 - s0);
      int r1 = r - 1;
      pB1 = *(const f32x4*)&gCt[r1o*1024 + t*4];
      pB2 = *(const f32x4*)&gLinv[r1o*1024 + t*4];
      if (ss == 0) {
        f32x4 a = *(const f32x4*)&gU[r1o*32 + oct*8];
        f32x4 b = *(const f32x4*)&gU[r1o*32 + oct*8 + 4];
        pg0[0]=a[0];pg0[1]=a[1];pg0[2]=a[2];pg0[3]=a[3];
        pg0[4]=b[0];pg0[5]=b[1];pg0[6]=b[2];pg0[7]=b[3];
      } else {
        load8(Eg, ((size_t)r1*64 + (ss-1))*32 + oct*8, bf, pg0);
      }
      load8(Eg, ((size_t)r1*64 + 63)*32 + oct*8, bf, pg1);
    }

    MM1(ss, gc0)
    if (t < 4) MM1(64, gc1)
    __syncthreads();

    MM2(ss)
    if (t < 4) MM2(64)
    __syncthreads();

    if (r < r0 + BBWD) {
      int j = t >> 2, c0 = (t & 3) * 8;
      f32x4 a0 = *(const f32x4*)&vw[(1+j)*LSTR + c0];
      f32x4 a1 = *(const f32x4*)&vw[(1+j)*LSTR + c0 + 4];
      f32x4 b0 = *(const f32x4*)&vw[c0];
      f32x4 b1 = *(const f32x4*)&vw[c0 + 4];
      f32x4 o0, o1;
      o0[0]=a0[0]+b0[0]; o0[1]=a0[1]+b0[1]; o0[2]=a0[2]+b0[2]; o0[3]=a0[3]+b0[3];
      o1[0]=a1[0]+b1[0]; o1[1]=a1[1]+b1[1]; o1[2]=a1[2]+b1[2]; o1[3]=a1[3]+b1[3];
      float* dst = outg + ((size_t)r*64 + j)*32 + c0;
      *(f32x4*)dst = o0;
      *(f32x4*)(dst + 4) = o1;
    }
  }
}

extern "C" void kernel_launch(void* const* d_in, const int* in_sizes, int n_in,
                              void* d_out, int out_size, void* d_ws, size_t ws_size,
                              hipStream_t stream) {
  (void)in_sizes; (void)n_in; (void)out_size;
  const void* H = d_in[0];   // x_hessian_diags [R,32,32] fp32
  const void* G = d_in[1];   // x_grads         [R,1,32]  fp32
  const void* M = d_in[2];   // x_trans_mat     [32,32]   fp32
  const void* W = d_in[3];   // x_trans_prec    [32,32]   fp32
  const void* I = d_in[4];   // x_init_prec     [32,32]   fp32
  const void* E = d_in[5];   // epsx            [R,64,32] fp32
  float* out = (float*)d_out;  // [R,64,32] fp32 (reference output dtype)

  int* flag = (int*)d_ws;                         // dtype flag (first 256 B reserved)
  float* ws0 = (float*)((char*)d_ws + 256);
  size_t avail = (ws_size > 256) ? (ws_size - 256) : 0;

  // Segment R so fp32 Linv/Ct/U (8320 B/row incl. +WBWD extension rows) fit.
  int nseg = 64;
  for (int cand = 1; cand <= 64; cand <<= 1) {
    size_t nrext = (size_t)(RTOT / cand) + WBWD;
    if (nrext * 8320 <= avail) { nseg = cand; break; }
  }
  const int segrows = RTOT / nseg;
  const size_t nrext_max = (size_t)segrows + WBWD;

  float* gLinv = ws0;
  float* gCt  = ws0 + nrext_max * 1024;
  float* gU   = ws0 + nrext_max * 2048;

  detect_kernel<<<1, 64, 0, stream>>>(W, flag);

  for (int s = 0; s < nseg; ++s) {
    int s0 = s * segrows;
    int s1ext = s0 + segrows + WBWD; if (s1ext > RTOT) s1ext = RTOT;
    int nfb = (s1ext - s0 + BFWD - 1) / BFWD;
    fwd_kernel<<<nfb, 64, 0, stream>>>(H, G, M, W, I, s0, flag, gLinv, gCt, gU);
    bwd_kernel<<<segrows / BBWD, 256, 0, stream>>>(E, gLinv, gCt, gU, out, s0, flag);
  }
}

// Round 4
// 646.473 us; speedup vs baseline: 2.4758x; 1.2398x over previous
//
#include <hip/hip_runtime.h>
#include <stdint.h>

#define RTOT 8192
#define BFWD 4      // rows produced per forward block (2048 blocks -> 2 waves/SIMD)
#define WFWD 24     // forward warmup steps (verified: absmax at bf16 floor)
#define BBWD 32     // rows per backward block (256 blocks; known-good config)
#define WBWD 24     // backward warmup steps
#define LSTR 36     // LDS row stride in floats

typedef unsigned short u16;
typedef __attribute__((ext_vector_type(4))) float f32x4;
typedef __attribute__((ext_vector_type(8))) unsigned short u16x8;

__device__ __forceinline__ float bf2f(u16 u) { return __uint_as_float(((uint32_t)u) << 16); }
__device__ __forceinline__ float rdlane(float v, int l) {
  return __int_as_float(__builtin_amdgcn_readlane(__float_as_int(v), l));
}

// Dual-dtype input loaders. bf==true: bf16 container; bf==false: fp32 container.
__device__ __forceinline__ void load8(const void* p, size_t off, bool bf, float* o) {
  if (bf) {
    u16x8 v = *(const u16x8*)((const u16*)p + off);
    #pragma unroll
    for (int e = 0; e < 8; ++e) o[e] = bf2f(v[e]);
  } else {
    f32x4 a = *(const f32x4*)((const float*)p + off);
    f32x4 b = *(const f32x4*)((const float*)p + off + 4);
    o[0]=a[0]; o[1]=a[1]; o[2]=a[2]; o[3]=a[3];
    o[4]=b[0]; o[5]=b[1]; o[6]=b[2]; o[7]=b[3];
  }
}
__device__ __forceinline__ float load1(const void* p, size_t off, bool bf) {
  return bf ? bf2f(((const u16*)p)[off]) : ((const float*)p)[off];
}

// ======================= DTYPE DETECTOR =======================
__global__ void detect_kernel(const void* Wptr, int* flag) {
  if (threadIdx.x == 0) {
    const u16* w = (const u16*)Wptr;
    int ok = 1;
    const int pi[4] = {0, 0, 1, 2};
    const int pj[4] = {1, 2, 2, 3};
    #pragma unroll
    for (int p = 0; p < 4; ++p)
      ok &= (w[pi[p]*32 + pj[p]] == w[pj[p]*32 + pi[p]]) ? 1 : 0;
    *flag = ok;   // 1 = bf16 container, 0 = fp32 container
  }
}

// ============================ FORWARD ============================
// One wave per block; rows [r0, r0+BFWD) after warmup from max(r0-WFWD,0).
// Half-wave specialization under SHARED instructions:
//  Schur phase (rank-32 update S -= Ct^T Ct): lane (h,il) updates elements
//  [16h,16h+16) of row il (lane-dep LDS offset hoff) -> halves FMA + LDS.
//  Reassembly: 16 shfl_xor(32) gather the full updated row into lower lanes;
//  upper lanes take mtpcol (MtP column) for the fused trisolve.
//  Chol phase: lower lanes = right-looking Cholesky rows; upper lanes =
//  Ct_new = Linv*MtP trisolve, same broadcasts bk = L[k][j], same fma.
//  u' = Linv*y fused scalar trisolve on the same rs.
//  Explicit Linv (stream w, lower lanes) only on output rows.
__global__ __launch_bounds__(64, 2) void fwd_kernel(
    const void* __restrict__ Hg, const void* __restrict__ Gg,
    const void* __restrict__ Mg, const void* __restrict__ Wg,
    const void* __restrict__ Ig, int s0, const int* __restrict__ flag,
    float* __restrict__ gLinv, float* __restrict__ gCt, float* __restrict__ gU)
{
  __shared__ __align__(16) float ldsCt[32*LSTR];    // setup: M stage, then MtPMt; loop: Ct
  __shared__ __align__(16) float ldsLinv[32*LSTR];  // setup: MtP; loop: Linv (output rows)
  __shared__ float ldsU[32];

  const bool bf = (*flag != 0);
  const int lane = threadIdx.x & 63;
  const int il = lane & 31;
  const bool lo = (lane < 32);
  const int hoff = (lane >> 5) * 16;   // element offset of this half-lane's slice

  // ---------------- setup ----------------
  float wrow[32], mrow[32];
  #pragma unroll
  for (int c = 0; c < 4; ++c) {
    float wt[8], mt[8];
    load8(Wg, il*32 + c*8, bf, wt);
    load8(Mg, il*32 + c*8, bf, mt);
    #pragma unroll
    for (int e = 0; e < 8; ++e) {
      wrow[c*8+e] = wt[e]; mrow[c*8+e] = mt[e];
      ldsCt[il*LSTR + c*8+e] = mt[e];          // stage M
    }
  }
  __syncthreads();

  // MtP[m][il] = sum_t M[m][t] * W[t][il]  (W symmetric) -> ldsLinv
  #pragma unroll 4
  for (int m = 0; m < 32; ++m) {
    float acc = 0.0f;
    #pragma unroll
    for (int c = 0; c < 8; ++c) {
      f32x4 q = *(const f32x4*)&ldsCt[m*LSTR + c*4];
      acc = fmaf(q[0], wrow[c*4+0], acc); acc = fmaf(q[1], wrow[c*4+1], acc);
      acc = fmaf(q[2], wrow[c*4+2], acc); acc = fmaf(q[3], wrow[c*4+3], acc);
    }
    ldsLinv[m*LSTR + il] = acc;
  }
  __syncthreads();
  // MtPMt[m][il] = sum_k MtP[m][k] * M[il][k] -> ldsCt (overwrites M)
  #pragma unroll 4
  for (int m = 0; m < 32; ++m) {
    float acc = 0.0f;
    #pragma unroll
    for (int c = 0; c < 8; ++c) {
      f32x4 q = *(const f32x4*)&ldsLinv[m*LSTR + c*4];
      acc = fmaf(q[0], mrow[c*4+0], acc); acc = fmaf(q[1], mrow[c*4+1], acc);
      acc = fmaf(q[2], mrow[c*4+2], acc); acc = fmaf(q[3], mrow[c*4+3], acc);
    }
    ldsCt[m*LSTR + il] = acc;
  }
  __syncthreads();

  float mtpcol[32];
  #pragma unroll
  for (int t = 0; t < 32; ++t) mtpcol[t] = ldsLinv[t*LSTR + il];
  // k0 half-slice: k0h[c] = W[il][hoff+c] + MtPMt[il][hoff+c]
  float k0h[16];
  #pragma unroll
  for (int c = 0; c < 16; ++c) {
    float a = wrow[c]      + ldsCt[il*LSTR + c];
    float b = wrow[c + 16] + ldsCt[il*LSTR + 16 + c];
    k0h[c] = lo ? a : b;
  }
  __syncthreads();

  // init running state: Ct = 0, u = 0
  #pragma unroll
  for (int k = 0; k < 32; ++k) ldsCt[il*LSTR + k] = 0.0f;
  if (lo) ldsU[il] = 0.0f;
  __syncthreads();

  const int r0 = s0 + blockIdx.x * BFWD;
  const int rw0 = (r0 >= WFWD) ? (r0 - WFWD) : 0;
  const int rend = r0 + BFWD;

  // H half-row prefetch: lane (h,il) loads H[il][hoff .. hoff+15]
  float hcur[16];
  #pragma unroll
  for (int c = 0; c < 2; ++c)
    load8(Hg, (size_t)rw0*1024 + il*32 + hoff + c*8, bf, &hcur[c*8]);
  float gv = load1(Gg, (size_t)rw0*32 + il, bf);

  for (int r = rw0; r < rend; ++r) {
    // prefetch next H half-row, g
    int rn = (r + 1 < RTOT) ? (r + 1) : r;
    float hnext[16];
    #pragma unroll
    for (int c = 0; c < 2; ++c)
      load8(Hg, (size_t)rn*1024 + il*32 + hoff + c*8, bf, &hnext[c*8]);
    float gvn = load1(Gg, (size_t)rn*32 + il, bf);

    // sv = half-slice of S base row (K0 + H, boundary variants)
    float sv[16];
    if (r == 0) {
      #pragma unroll
      for (int c = 0; c < 2; ++c) {
        float it[8], wt[8];
        load8(Ig, il*32 + hoff + c*8, bf, it);
        load8(Wg, il*32 + hoff + c*8, bf, wt);
        #pragma unroll
        for (int e = 0; e < 8; ++e)
          sv[c*8+e] = hcur[c*8+e] + it[e] + (k0h[c*8+e] - wt[e]);  // H + I + MtPMt
      }
    } else if (r == RTOT - 1) {   // m_s = 0: S = H + W
      #pragma unroll
      for (int c = 0; c < 2; ++c) {
        float wt[8];
        load8(Wg, il*32 + hoff + c*8, bf, wt);
        #pragma unroll
        for (int e = 0; e < 8; ++e) sv[c*8+e] = hcur[c*8+e] + wt[e];
      }
    } else {
      #pragma unroll
      for (int k = 0; k < 16; ++k) sv[k] = hcur[k] + k0h[k];
    }

    // split Schur: sv[c] -= cm * Ct[m][hoff+c]; y = g + sum u[m]*Ct[m][il]
    // (cm identical in paired lanes -> y valid in both halves)
    float y = gv;
    #pragma unroll 4
    for (int m = 0; m < 32; ++m) {
      float cm = ldsCt[m*LSTR + il];
      y = fmaf(ldsU[m], cm, y);
      #pragma unroll
      for (int c = 0; c < 4; ++c) {
        f32x4 q = *(const f32x4*)&ldsCt[m*LSTR + hoff + c*4];
        sv[c*4+0] = fmaf(-cm, q[0], sv[c*4+0]);
        sv[c*4+1] = fmaf(-cm, q[1], sv[c*4+1]);
        sv[c*4+2] = fmaf(-cm, q[2], sv[c*4+2]);
        sv[c*4+3] = fmaf(-cm, q[3], sv[c*4+3]);
      }
    }

    // reassemble: lower gets full updated row; upper gets MtP column
    float v[32];
    #pragma unroll
    for (int c = 0; c < 16; ++c) {
      float o = __shfl_xor(sv[c], 32, 64);
      v[c]      = lo ? sv[c] : mtpcol[c];
      v[c + 16] = lo ? o     : mtpcol[c + 16];
    }

    float un = 0.0f;
    float yr = y;
    if (r < r0) {
      // warmup: chol (lower) + Ct trisolve (upper) + u trisolve (scalar chain)
      #pragma unroll
      for (int j = 0; j < 32; ++j) {
        float dj = fmaxf(rdlane(v[j], j), 1e-12f);
        float rs = __builtin_amdgcn_rsqf(dj);
        float a = v[j] * rs;            // lower: L[il][j]; upper: Ct_new[j][il]
        v[j] = a;
        float uj = rdlane(yr, j) * rs;  // u'[j]  (1/L[jj] == rs)
        yr = fmaf(-a, uj, yr);
        if (il == j) un = uj;
        #pragma unroll
        for (int k = j + 1; k < 32; ++k) {
          float bk = rdlane(v[j], k);   // L[k][j]
          v[k] = fmaf(-a, bk, v[k]);
        }
      }
    } else {
      // output row: also maintain explicit Linv (stream w, lower lanes)
      float w[32];
      #pragma unroll
      for (int i = 0; i < 32; ++i) w[i] = (lo && il == i) ? 1.0f : 0.0f;
      #pragma unroll
      for (int j = 0; j < 32; ++j) {
        float dj = fmaxf(rdlane(v[j], j), 1e-12f);
        float rs = __builtin_amdgcn_rsqf(dj);
        float a = v[j] * rs;
        v[j] = a;
        float b = w[j] * rs;            // lower: Linv[j][il]
        w[j] = b;
        float uj = rdlane(yr, j) * rs;
        yr = fmaf(-a, uj, yr);
        if (il == j) un = uj;
        #pragma unroll
        for (int k = j + 1; k < 32; ++k) {
          float bk = rdlane(v[j], k);
          v[k] = fmaf(-a, bk, v[k]);
          w[k] = fmaf(-b, bk, w[k]);
        }
      }
      if (lo) {
        #pragma unroll
        for (int i = 0; i < 32; ++i) ldsLinv[i*LSTR + il] = w[i];
      }
    }

    // commit new Ct (upper lanes) and u (lower lanes); single wave -> DS ops
    // are in-order, no barrier needed between iterations.
    if (!lo) {
      #pragma unroll
      for (int m = 0; m < 32; ++m) ldsCt[m*LSTR + il] = v[m];
    } else {
      ldsU[il] = un;
    }

    if (r >= r0) {
      __syncthreads();
      size_t ro = (size_t)(r - s0);
      #pragma unroll
      for (int c = 0; c < 4; ++c) {
        int f = lane*16 + c*4;
        int mm = f >> 5, kk = f & 31;
        *(f32x4*)&gLinv[ro*1024 + f] = *(const f32x4*)&ldsLinv[mm*LSTR + kk];
        *(f32x4*)&gCt [ro*1024 + f] = *(const f32x4*)&ldsCt [mm*LSTR + kk];
      }
      if (lo) gU[ro*32 + il] = un;
    }

    #pragma unroll
    for (int e = 0; e < 16; ++e) hcur[e] = hnext[e];
    gv = gvn;
  }
}

// ============================ BACKWARD ============================
// (round-0 configuration: BBWD=32, launch_bounds(256,1) — known-good)
//   X[s][k]   = G[s][k] + sum_m vw[s][m] * B1[k][m]   (B1 = Ct row-major)
//   vw'[s][j] = sum_k X[s][k] * B2[k][j]              (B2 = Linv row-major)
//   out[r][j][:] = vw'[0][:] + vw'[1+j][:]   (fp32 output)
#define MM1(SVAL, GARR)                                                   \
  { int s_ = (SVAL);                                                      \
    float vr[32];                                                         \
    _Pragma("unroll")                                                     \
    for (int c = 0; c < 8; ++c) {                                         \
      f32x4 q = *(const f32x4*)&vw[s_*LSTR + c*4];                        \
      vr[c*4+0]=q[0]; vr[c*4+1]=q[1]; vr[c*4+2]=q[2]; vr[c*4+3]=q[3];     \
    }                                                                     \
    float xr[8];                                                          \
    _Pragma("unroll")                                                     \
    for (int e = 0; e < 8; ++e) {                                         \
      int k_ = oct*8 + e;                                                 \
      float acc = GARR[e];                                                \
      _Pragma("unroll")                                                   \
      for (int c = 0; c < 8; ++c) {                                       \
        f32x4 b = *(const f32x4*)&B1[k_*LSTR + c*4];                      \
        acc = fmaf(vr[c*4+0], b[0], acc);                                 \
        acc = fmaf(vr[c*4+1], b[1], acc);                                 \
        acc = fmaf(vr[c*4+2], b[2], acc);                                 \
        acc = fmaf(vr[c*4+3], b[3], acc);                                 \
      }                                                                   \
      xr[e] = acc;                                                       \
    }                                                                     \
    f32x4 xa = { xr[0], xr[1], xr[2], xr[3] };                            \
    f32x4 xb = { xr[4], xr[5], xr[6], xr[7] };                            \
    *(f32x4*)&Xs[s_*LSTR + oct*8] = xa;                                   \
    *(f32x4*)&Xs[s_*LSTR + oct*8 + 4] = xb;                               \
  }

#define MM2(SVAL)                                                         \
  { int s_ = (SVAL);                                                      \
    float xrr[32];                                                        \
    _Pragma("unroll")                                                     \
    for (int c = 0; c < 8; ++c) {                                         \
      f32x4 q = *(const f32x4*)&Xs[s_*LSTR + c*4];                        \
      xrr[c*4+0]=q[0]; xrr[c*4+1]=q[1]; xrr[c*4+2]=q[2]; xrr[c*4+3]=q[3]; \
    }                                                                     \
    float a0=0,a1=0,a2=0,a3=0,a4=0,a5=0,a6=0,a7=0;                        \
    _Pragma("unroll")                                                     \
    for (int k_ = 0; k_ < 32; ++k_) {                                     \
      f32x4 b = *(const f32x4*)&B2[k_*LSTR + oct*8];                      \
      f32x4 b2 = *(const f32x4*)&B2[k_*LSTR + oct*8 + 4];                 \
      float xk = xrr[k_];                                                 \
      a0 = fmaf(xk, b[0], a0);  a1 = fmaf(xk, b[1], a1);                  \
      a2 = fmaf(xk, b[2], a2);  a3 = fmaf(xk, b[3], a3);                  \
      a4 = fmaf(xk, b2[0], a4); a5 = fmaf(xk, b2[1], a5);                 \
      a6 = fmaf(xk, b2[2], a6); a7 = fmaf(xk, b2[3], a7);                 \
    }                                                                     \
    f32x4 va = { a0, a1, a2, a3 };                                        \
    f32x4 vb = { a4, a5, a6, a7 };                                        \
    *(f32x4*)&vw[s_*LSTR + oct*8] = va;                                   \
    *(f32x4*)&vw[s_*LSTR + oct*8 + 4] = vb;                               \
  }

__global__ __launch_bounds__(256, 1) void bwd_kernel(
    const void* __restrict__ Eg,
    const float* __restrict__ gLinv, const float* __restrict__ gCt,
    const float* __restrict__ gU, float* __restrict__ outg, int s0,
    const int* __restrict__ flag)
{
  __shared__ __align__(16) float vw[65*LSTR];
  __shared__ __align__(16) float Xs[65*LSTR];
  __shared__ __align__(16) float B1[32*LSTR];
  __shared__ __align__(16) float B2[32*LSTR];

  const bool bf = (*flag != 0);
  const int t = threadIdx.x;
  const int ss = t >> 2;
  const int oct = t & 3;

  const int r0 = s0 + blockIdx.x * BBWD;
  int re = r0 + BBWD - 1 + WBWD; if (re > RTOT-1) re = RTOT-1;

  for (int i = t; i < 65*LSTR; i += 256) vw[i] = 0.0f;

  // prefetch for r = re
  size_t reo = (size_t)(re - s0);
  f32x4 pB1 = *(const f32x4*)&gCt[reo*1024 + t*4];
  f32x4 pB2 = *(const f32x4*)&gLinv[reo*1024 + t*4];
  float pg0[8], pg1[8];
  if (ss == 0) {
    f32x4 a = *(const f32x4*)&gU[reo*32 + oct*8];
    f32x4 b = *(const f32x4*)&gU[reo*32 + oct*8 + 4];
    pg0[0]=a[0];pg0[1]=a[1];pg0[2]=a[2];pg0[3]=a[3];
    pg0[4]=b[0];pg0[5]=b[1];pg0[6]=b[2];pg0[7]=b[3];
  } else {
    load8(Eg, ((size_t)re*64 + (ss-1))*32 + oct*8, bf, pg0);
  }
  load8(Eg, ((size_t)re*64 + 63)*32 + oct*8, bf, pg1);

  float gc0[8], gc1[8];

  for (int r = re; r >= r0; --r) {
    { // stage prefetched B1/B2/G
      int mm = t >> 3, kk = (t & 7) * 4;
      *(f32x4*)&B1[mm*LSTR + kk] = pB1;
      *(f32x4*)&B2[mm*LSTR + kk] = pB2;
      #pragma unroll
      for (int e = 0; e < 8; ++e) { gc0[e] = pg0[e]; gc1[e] = pg1[e]; }
    }
    __syncthreads();

    if (r > r0) {  // issue prefetch for r-1
      size_t r1o = (size_t)(r - 1 - s0);
      int r1 = r - 1;
      pB1 = *(const f32x4*)&gCt[r1o*1024 + t*4];
      pB2 = *(const f32x4*)&gLinv[r1o*1024 + t*4];
      if (ss == 0) {
        f32x4 a = *(const f32x4*)&gU[r1o*32 + oct*8];
        f32x4 b = *(const f32x4*)&gU[r1o*32 + oct*8 + 4];
        pg0[0]=a[0];pg0[1]=a[1];pg0[2]=a[2];pg0[3]=a[3];
        pg0[4]=b[0];pg0[5]=b[1];pg0[6]=b[2];pg0[7]=b[3];
      } else {
        load8(Eg, ((size_t)r1*64 + (ss-1))*32 + oct*8, bf, pg0);
      }
      load8(Eg, ((size_t)r1*64 + 63)*32 + oct*8, bf, pg1);
    }

    MM1(ss, gc0)
    if (t < 4) MM1(64, gc1)
    __syncthreads();

    MM2(ss)
    if (t < 4) MM2(64)
    __syncthreads();

    if (r < r0 + BBWD) {
      int j = t >> 2, c0 = (t & 3) * 8;
      f32x4 a0 = *(const f32x4*)&vw[(1+j)*LSTR + c0];
      f32x4 a1 = *(const f32x4*)&vw[(1+j)*LSTR + c0 + 4];
      f32x4 b0 = *(const f32x4*)&vw[c0];
      f32x4 b1 = *(const f32x4*)&vw[c0 + 4];
      f32x4 o0, o1;
      o0[0]=a0[0]+b0[0]; o0[1]=a0[1]+b0[1]; o0[2]=a0[2]+b0[2]; o0[3]=a0[3]+b0[3];
      o1[0]=a1[0]+b1[0]; o1[1]=a1[1]+b1[1]; o1[2]=a1[2]+b1[2]; o1[3]=a1[3]+b1[3];
      float* dst = outg + ((size_t)r*64 + j)*32 + c0;
      *(f32x4*)dst = o0;
      *(f32x4*)(dst + 4) = o1;
    }
  }
}

extern "C" void kernel_launch(void* const* d_in, const int* in_sizes, int n_in,
                              void* d_out, int out_size, void* d_ws, size_t ws_size,
                              hipStream_t stream) {
  (void)in_sizes; (void)n_in; (void)out_size;
  const void* H = d_in[0];   // x_hessian_diags [R,32,32] fp32
  const void* G = d_in[1];   // x_grads         [R,1,32]  fp32
  const void* M = d_in[2];   // x_trans_mat     [32,32]   fp32
  const void* W = d_in[3];   // x_trans_prec    [32,32]   fp32
  const void* I = d_in[4];   // x_init_prec     [32,32]   fp32
  const void* E = d_in[5];   // epsx            [R,64,32] fp32
  float* out = (float*)d_out;  // [R,64,32] fp32 (reference output dtype)

  int* flag = (int*)d_ws;                         // dtype flag (first 256 B reserved)
  float* ws0 = (float*)((char*)d_ws + 256);
  size_t avail = (ws_size > 256) ? (ws_size - 256) : 0;

  // Segment R so fp32 Linv/Ct/U (8320 B/row incl. +WBWD extension rows) fit.
  int nseg = 64;
  for (int cand = 1; cand <= 64; cand <<= 1) {
    size_t nrext = (size_t)(RTOT / cand) + WBWD;
    if (nrext * 8320 <= avail) { nseg = cand; break; }
  }
  const int segrows = RTOT / nseg;
  const size_t nrext_max = (size_t)segrows + WBWD;

  float* gLinv = ws0;
  float* gCt  = ws0 + nrext_max * 1024;
  float* gU   = ws0 + nrext_max * 2048;

  detect_kernel<<<1, 64, 0, stream>>>(W, flag);

  for (int s = 0; s < nseg; ++s) {
    int s0 = s * segrows;
    int s1ext = s0 + segrows + WBWD; if (s1ext > RTOT) s1ext = RTOT;
    int nfb = (s1ext - s0 + BFWD - 1) / BFWD;
    fwd_kernel<<<nfb, 64, 0, stream>>>(H, G, M, W, I, s0, flag, gLinv, gCt, gU);
    bwd_kernel<<<segrows / BBWD, 256, 0, stream>>>(E, gLinv, gCt, gU, out, s0, flag);
  }
}

// Round 5
// 556.908 us; speedup vs baseline: 2.8740x; 1.1608x over previous
//
#include <hip/hip_runtime.h>
#include <stdint.h>

#define RTOT 8192
#define BFWD 4      // rows produced per forward block (2048 blocks -> 2 waves/SIMD)
#define WFWD 24     // forward warmup steps (verified: absmax at bf16 floor)
#define BBWD 32     // rows per backward block (256 blocks; known-good config)
#define WBWD 24     // backward warmup steps
#define LSTR 36     // LDS row stride in floats

typedef unsigned short u16;
typedef __attribute__((ext_vector_type(4))) float f32x4;
typedef __attribute__((ext_vector_type(8))) unsigned short u16x8;

__device__ __forceinline__ float bf2f(u16 u) { return __uint_as_float(((uint32_t)u) << 16); }
__device__ __forceinline__ float rdlane(float v, int l) {
  return __int_as_float(__builtin_amdgcn_readlane(__float_as_int(v), l));
}

// Dual-dtype input loaders. bf==true: bf16 container; bf==false: fp32 container.
__device__ __forceinline__ void load8(const void* p, size_t off, bool bf, float* o) {
  if (bf) {
    u16x8 v = *(const u16x8*)((const u16*)p + off);
    #pragma unroll
    for (int e = 0; e < 8; ++e) o[e] = bf2f(v[e]);
  } else {
    f32x4 a = *(const f32x4*)((const float*)p + off);
    f32x4 b = *(const f32x4*)((const float*)p + off + 4);
    o[0]=a[0]; o[1]=a[1]; o[2]=a[2]; o[3]=a[3];
    o[4]=b[0]; o[5]=b[1]; o[6]=b[2]; o[7]=b[3];
  }
}
__device__ __forceinline__ float load1(const void* p, size_t off, bool bf) {
  return bf ? bf2f(((const u16*)p)[off]) : ((const float*)p)[off];
}

// ======================= DTYPE DETECTOR =======================
__global__ void detect_kernel(const void* Wptr, int* flag) {
  if (threadIdx.x == 0) {
    const u16* w = (const u16*)Wptr;
    int ok = 1;
    const int pi[4] = {0, 0, 1, 2};
    const int pj[4] = {1, 2, 2, 3};
    #pragma unroll
    for (int p = 0; p < 4; ++p)
      ok &= (w[pi[p]*32 + pj[p]] == w[pj[p]*32 + pi[p]]) ? 1 : 0;
    *flag = ok;   // 1 = bf16 container, 0 = fp32 container
  }
}

// ============================ FORWARD ============================
// (unchanged from round 4 — proven 296 us)
__global__ __launch_bounds__(64, 2) void fwd_kernel(
    const void* __restrict__ Hg, const void* __restrict__ Gg,
    const void* __restrict__ Mg, const void* __restrict__ Wg,
    const void* __restrict__ Ig, int s0, const int* __restrict__ flag,
    float* __restrict__ gLinv, float* __restrict__ gCt, float* __restrict__ gU)
{
  __shared__ __align__(16) float ldsCt[32*LSTR];
  __shared__ __align__(16) float ldsLinv[32*LSTR];
  __shared__ float ldsU[32];

  const bool bf = (*flag != 0);
  const int lane = threadIdx.x & 63;
  const int il = lane & 31;
  const bool lo = (lane < 32);
  const int hoff = (lane >> 5) * 16;

  float wrow[32], mrow[32];
  #pragma unroll
  for (int c = 0; c < 4; ++c) {
    float wt[8], mt[8];
    load8(Wg, il*32 + c*8, bf, wt);
    load8(Mg, il*32 + c*8, bf, mt);
    #pragma unroll
    for (int e = 0; e < 8; ++e) {
      wrow[c*8+e] = wt[e]; mrow[c*8+e] = mt[e];
      ldsCt[il*LSTR + c*8+e] = mt[e];
    }
  }
  __syncthreads();

  #pragma unroll 4
  for (int m = 0; m < 32; ++m) {
    float acc = 0.0f;
    #pragma unroll
    for (int c = 0; c < 8; ++c) {
      f32x4 q = *(const f32x4*)&ldsCt[m*LSTR + c*4];
      acc = fmaf(q[0], wrow[c*4+0], acc); acc = fmaf(q[1], wrow[c*4+1], acc);
      acc = fmaf(q[2], wrow[c*4+2], acc); acc = fmaf(q[3], wrow[c*4+3], acc);
    }
    ldsLinv[m*LSTR + il] = acc;
  }
  __syncthreads();
  #pragma unroll 4
  for (int m = 0; m < 32; ++m) {
    float acc = 0.0f;
    #pragma unroll
    for (int c = 0; c < 8; ++c) {
      f32x4 q = *(const f32x4*)&ldsLinv[m*LSTR + c*4];
      acc = fmaf(q[0], mrow[c*4+0], acc); acc = fmaf(q[1], mrow[c*4+1], acc);
      acc = fmaf(q[2], mrow[c*4+2], acc); acc = fmaf(q[3], mrow[c*4+3], acc);
    }
    ldsCt[m*LSTR + il] = acc;
  }
  __syncthreads();

  float mtpcol[32];
  #pragma unroll
  for (int t = 0; t < 32; ++t) mtpcol[t] = ldsLinv[t*LSTR + il];
  float k0h[16];
  #pragma unroll
  for (int c = 0; c < 16; ++c) {
    float a = wrow[c]      + ldsCt[il*LSTR + c];
    float b = wrow[c + 16] + ldsCt[il*LSTR + 16 + c];
    k0h[c] = lo ? a : b;
  }
  __syncthreads();

  #pragma unroll
  for (int k = 0; k < 32; ++k) ldsCt[il*LSTR + k] = 0.0f;
  if (lo) ldsU[il] = 0.0f;
  __syncthreads();

  const int r0 = s0 + blockIdx.x * BFWD;
  const int rw0 = (r0 >= WFWD) ? (r0 - WFWD) : 0;
  const int rend = r0 + BFWD;

  float hcur[16];
  #pragma unroll
  for (int c = 0; c < 2; ++c)
    load8(Hg, (size_t)rw0*1024 + il*32 + hoff + c*8, bf, &hcur[c*8]);
  float gv = load1(Gg, (size_t)rw0*32 + il, bf);

  for (int r = rw0; r < rend; ++r) {
    int rn = (r + 1 < RTOT) ? (r + 1) : r;
    float hnext[16];
    #pragma unroll
    for (int c = 0; c < 2; ++c)
      load8(Hg, (size_t)rn*1024 + il*32 + hoff + c*8, bf, &hnext[c*8]);
    float gvn = load1(Gg, (size_t)rn*32 + il, bf);

    float sv[16];
    if (r == 0) {
      #pragma unroll
      for (int c = 0; c < 2; ++c) {
        float it[8], wt[8];
        load8(Ig, il*32 + hoff + c*8, bf, it);
        load8(Wg, il*32 + hoff + c*8, bf, wt);
        #pragma unroll
        for (int e = 0; e < 8; ++e)
          sv[c*8+e] = hcur[c*8+e] + it[e] + (k0h[c*8+e] - wt[e]);
      }
    } else if (r == RTOT - 1) {
      #pragma unroll
      for (int c = 0; c < 2; ++c) {
        float wt[8];
        load8(Wg, il*32 + hoff + c*8, bf, wt);
        #pragma unroll
        for (int e = 0; e < 8; ++e) sv[c*8+e] = hcur[c*8+e] + wt[e];
      }
    } else {
      #pragma unroll
      for (int k = 0; k < 16; ++k) sv[k] = hcur[k] + k0h[k];
    }

    float y = gv;
    #pragma unroll 4
    for (int m = 0; m < 32; ++m) {
      float cm = ldsCt[m*LSTR + il];
      y = fmaf(ldsU[m], cm, y);
      #pragma unroll
      for (int c = 0; c < 4; ++c) {
        f32x4 q = *(const f32x4*)&ldsCt[m*LSTR + hoff + c*4];
        sv[c*4+0] = fmaf(-cm, q[0], sv[c*4+0]);
        sv[c*4+1] = fmaf(-cm, q[1], sv[c*4+1]);
        sv[c*4+2] = fmaf(-cm, q[2], sv[c*4+2]);
        sv[c*4+3] = fmaf(-cm, q[3], sv[c*4+3]);
      }
    }

    float v[32];
    #pragma unroll
    for (int c = 0; c < 16; ++c) {
      float o = __shfl_xor(sv[c], 32, 64);
      v[c]      = lo ? sv[c] : mtpcol[c];
      v[c + 16] = lo ? o     : mtpcol[c + 16];
    }

    float un = 0.0f;
    float yr = y;
    if (r < r0) {
      #pragma unroll
      for (int j = 0; j < 32; ++j) {
        float dj = fmaxf(rdlane(v[j], j), 1e-12f);
        float rs = __builtin_amdgcn_rsqf(dj);
        float a = v[j] * rs;
        v[j] = a;
        float uj = rdlane(yr, j) * rs;
        yr = fmaf(-a, uj, yr);
        if (il == j) un = uj;
        #pragma unroll
        for (int k = j + 1; k < 32; ++k) {
          float bk = rdlane(v[j], k);
          v[k] = fmaf(-a, bk, v[k]);
        }
      }
    } else {
      float w[32];
      #pragma unroll
      for (int i = 0; i < 32; ++i) w[i] = (lo && il == i) ? 1.0f : 0.0f;
      #pragma unroll
      for (int j = 0; j < 32; ++j) {
        float dj = fmaxf(rdlane(v[j], j), 1e-12f);
        float rs = __builtin_amdgcn_rsqf(dj);
        float a = v[j] * rs;
        v[j] = a;
        float b = w[j] * rs;
        w[j] = b;
        float uj = rdlane(yr, j) * rs;
        yr = fmaf(-a, uj, yr);
        if (il == j) un = uj;
        #pragma unroll
        for (int k = j + 1; k < 32; ++k) {
          float bk = rdlane(v[j], k);
          v[k] = fmaf(-a, bk, v[k]);
          w[k] = fmaf(-b, bk, w[k]);
        }
      }
      if (lo) {
        #pragma unroll
        for (int i = 0; i < 32; ++i) ldsLinv[i*LSTR + il] = w[i];
      }
    }

    if (!lo) {
      #pragma unroll
      for (int m = 0; m < 32; ++m) ldsCt[m*LSTR + il] = v[m];
    } else {
      ldsU[il] = un;
    }

    if (r >= r0) {
      __syncthreads();
      size_t ro = (size_t)(r - s0);
      #pragma unroll
      for (int c = 0; c < 4; ++c) {
        int f = lane*16 + c*4;
        int mm = f >> 5, kk = f & 31;
        *(f32x4*)&gLinv[ro*1024 + f] = *(const f32x4*)&ldsLinv[mm*LSTR + kk];
        *(f32x4*)&gCt [ro*1024 + f] = *(const f32x4*)&ldsCt [mm*LSTR + kk];
      }
      if (lo) gU[ro*32 + il] = un;
    }

    #pragma unroll
    for (int e = 0; e < 16; ++e) hcur[e] = hnext[e];
    gv = gvn;
  }
}

// ============================ MID ============================
// Fully parallel per-row transform (one block per row):
//   Ye[s][j] = sum_k eps[r][s][k] * Linv[k][j]   (s=0..63)
//   Y0[j]    = sum_k u[k] * Linv[k][j]
//   D[m][j]  = sum_k Ct[k][m] * Linv[k][j]
// In-place: D -> gCt, Ye[0:32] -> gLinv, Ye[32:64] -> gY2, Y0 -> gU.
// All global reads are LDS-staged before the barrier, so in-place is safe.
__global__ __launch_bounds__(256, 2) void mid_kernel(
    const void* __restrict__ Eg, const int* __restrict__ flag,
    float* __restrict__ gLinv, float* __restrict__ gCt,
    float* __restrict__ gU, float* __restrict__ gY2, int s0)
{
  __shared__ __align__(16) float Li[32*LSTR];
  __shared__ __align__(16) float Ct_[32*LSTR];
  __shared__ float Ut[32];

  const bool bf = (*flag != 0);
  const int t = threadIdx.x;
  const size_t ro = blockIdx.x;
  const size_t r = (size_t)s0 + ro;

  {
    int mm = t >> 3, kk = (t & 7) * 4;
    *(f32x4*)&Li[mm*LSTR + kk]  = *(const f32x4*)&gLinv[ro*1024 + t*4];
    *(f32x4*)&Ct_[mm*LSTR + kk] = *(const f32x4*)&gCt [ro*1024 + t*4];
    if (t < 32) Ut[t] = gU[ro*32 + t];
  }
  __syncthreads();

  // Ye: thread (s = t>>2, oct = t&3) computes 8 j's of eps-row s
  {
    int s = t >> 2, oct = t & 3;
    float er[32];
    #pragma unroll
    for (int c = 0; c < 4; ++c) load8(Eg, (r*64 + (size_t)s)*32 + c*8, bf, &er[c*8]);
    float a0=0,a1=0,a2=0,a3=0,a4=0,a5=0,a6=0,a7=0;
    #pragma unroll 4
    for (int k = 0; k < 32; ++k) {
      f32x4 b  = *(const f32x4*)&Li[k*LSTR + oct*8];
      f32x4 b2 = *(const f32x4*)&Li[k*LSTR + oct*8 + 4];
      float ek = er[k];
      a0=fmaf(ek,b[0],a0);  a1=fmaf(ek,b[1],a1);
      a2=fmaf(ek,b[2],a2);  a3=fmaf(ek,b[3],a3);
      a4=fmaf(ek,b2[0],a4); a5=fmaf(ek,b2[1],a5);
      a6=fmaf(ek,b2[2],a6); a7=fmaf(ek,b2[3],a7);
    }
    float* dst = (s < 32) ? (gLinv + ro*1024 + (size_t)s*32)
                          : (gY2  + ro*1024 + (size_t)(s-32)*32);
    f32x4 va = {a0,a1,a2,a3}, vb = {a4,a5,a6,a7};
    *(f32x4*)&dst[oct*8] = va;
    *(f32x4*)&dst[oct*8 + 4] = vb;
  }

  // D: thread (m = t>>3, jo = t&7) computes D[m][jo*4 .. +4]
  {
    int m = t >> 3, jo = t & 7;
    float d0=0,d1=0,d2=0,d3=0;
    #pragma unroll 4
    for (int k = 0; k < 32; ++k) {
      float cv = Ct_[k*LSTR + m];
      f32x4 b = *(const f32x4*)&Li[k*LSTR + jo*4];
      d0=fmaf(cv,b[0],d0); d1=fmaf(cv,b[1],d1);
      d2=fmaf(cv,b[2],d2); d3=fmaf(cv,b[3],d3);
    }
    f32x4 dv = {d0,d1,d2,d3};
    *(f32x4*)&gCt[ro*1024 + (size_t)m*32 + jo*4] = dv;
  }

  // Y0
  if (t < 32) {
    float a = 0.0f;
    #pragma unroll
    for (int k = 0; k < 32; ++k) a = fmaf(Ut[k], Li[k*LSTR + t], a);
    gU[ro*32 + t] = a;
  }
}

// ============================ BACKWARD ============================
// Single matmul per step: vw'[s] = Y[s] + vw[s] * D   (65x32 · 32x32)
// Each vw row is owned by 4 threads of one wave (same-wave DS ordering ->
// no barrier for vw). D double-buffered in LDS, one barrier per step.
// Row 0 broadcast for the out-write via double-buffered v0buf.
__global__ __launch_bounds__(256, 1) void bwd_kernel(
    const float* __restrict__ gD,   // = gCt region (D after mid)
    const float* __restrict__ gY1,  // = gLinv region (Ye rows 0..31)
    const float* __restrict__ gY2,  // Ye rows 32..63
    const float* __restrict__ gY0,  // = gU region (Y0)
    float* __restrict__ outg, int s0)
{
  __shared__ __align__(16) float vw[65*LSTR];
  __shared__ __align__(16) float Dl[2][32*LSTR];
  __shared__ __align__(16) float v0buf[2][32];

  const int t = threadIdx.x;
  const int ss = t >> 2;
  const int oct = t & 3;
  const int r0 = s0 + blockIdx.x * BBWD;
  int re = r0 + BBWD - 1 + WBWD; if (re > RTOT - 1) re = RTOT - 1;

  f32x4 z = {0,0,0,0};
  *(f32x4*)&vw[ss*LSTR + oct*8] = z;
  *(f32x4*)&vw[ss*LSTR + oct*8 + 4] = z;
  if (t < 4) {
    *(f32x4*)&vw[64*LSTR + oct*8] = z;
    *(f32x4*)&vw[64*LSTR + oct*8 + 4] = z;
  }

  #define YPTR(RO_, S_) \
    ((S_) == 0  ? (gY0 + (size_t)(RO_)*32) : \
     (S_) <= 32 ? (gY1 + (size_t)(RO_)*1024 + (size_t)((S_)-1)*32) \
                : (gY2 + (size_t)(RO_)*1024 + (size_t)((S_)-33)*32))

  // prologue for r = re
  const int reo = re - s0;
  f32x4 pD = *(const f32x4*)&gD[(size_t)reo*1024 + t*4];
  f32x4 yA, yB, y2A = z, y2B = z;
  { const float* yb = YPTR(reo, ss);
    yA = *(const f32x4*)&yb[oct*8]; yB = *(const f32x4*)&yb[oct*8 + 4]; }
  if (t < 4) { const float* yb = YPTR(reo, 64);
    y2A = *(const f32x4*)&yb[oct*8]; y2B = *(const f32x4*)&yb[oct*8 + 4]; }
  *(f32x4*)&Dl[re & 1][(t>>3)*LSTR + (t&7)*4] = pD;
  if (re > r0) pD = *(const f32x4*)&gD[(size_t)(reo-1)*1024 + t*4];
  __syncthreads();

  for (int r = re; r >= r0; --r) {
    const int cur = r & 1;
    const int ro = r - s0;

    // main row ss
    float vr[32];
    #pragma unroll
    for (int c = 0; c < 8; ++c) {
      f32x4 q = *(const f32x4*)&vw[ss*LSTR + c*4];
      vr[c*4+0]=q[0]; vr[c*4+1]=q[1]; vr[c*4+2]=q[2]; vr[c*4+3]=q[3];
    }
    float a0=yA[0],a1=yA[1],a2=yA[2],a3=yA[3];
    float a4=yB[0],a5=yB[1],a6=yB[2],a7=yB[3];
    #pragma unroll 4
    for (int k = 0; k < 32; ++k) {
      f32x4 b  = *(const f32x4*)&Dl[cur][k*LSTR + oct*8];
      f32x4 b2 = *(const f32x4*)&Dl[cur][k*LSTR + oct*8 + 4];
      float xk = vr[k];
      a0=fmaf(xk,b[0],a0);  a1=fmaf(xk,b[1],a1);
      a2=fmaf(xk,b[2],a2);  a3=fmaf(xk,b[3],a3);
      a4=fmaf(xk,b2[0],a4); a5=fmaf(xk,b2[1],a5);
      a6=fmaf(xk,b2[2],a6); a7=fmaf(xk,b2[3],a7);
    }
    f32x4 va = {a0,a1,a2,a3}, vb = {a4,a5,a6,a7};
    *(f32x4*)&vw[ss*LSTR + oct*8] = va;
    *(f32x4*)&vw[ss*LSTR + oct*8 + 4] = vb;
    if (t < 4) {   // this thread's main row IS row 0 -> broadcast copy
      *(f32x4*)&v0buf[cur][oct*8] = va;
      *(f32x4*)&v0buf[cur][oct*8 + 4] = vb;
    }

    // extra row 64 on t<4
    float e0=0,e1=0,e2=0,e3=0,e4=0,e5=0,e6=0,e7=0;
    if (t < 4) {
      float vr2[32];
      #pragma unroll
      for (int c = 0; c < 8; ++c) {
        f32x4 q = *(const f32x4*)&vw[64*LSTR + c*4];
        vr2[c*4+0]=q[0]; vr2[c*4+1]=q[1]; vr2[c*4+2]=q[2]; vr2[c*4+3]=q[3];
      }
      e0=y2A[0];e1=y2A[1];e2=y2A[2];e3=y2A[3];
      e4=y2B[0];e5=y2B[1];e6=y2B[2];e7=y2B[3];
      #pragma unroll 4
      for (int k = 0; k < 32; ++k) {
        f32x4 b  = *(const f32x4*)&Dl[cur][k*LSTR + oct*8];
        f32x4 b2 = *(const f32x4*)&Dl[cur][k*LSTR + oct*8 + 4];
        float xk = vr2[k];
        e0=fmaf(xk,b[0],e0);  e1=fmaf(xk,b[1],e1);
        e2=fmaf(xk,b[2],e2);  e3=fmaf(xk,b[3],e3);
        e4=fmaf(xk,b2[0],e4); e5=fmaf(xk,b2[1],e5);
        e6=fmaf(xk,b2[2],e6); e7=fmaf(xk,b2[3],e7);
      }
      f32x4 ea = {e0,e1,e2,e3}, eb = {e4,e5,e6,e7};
      *(f32x4*)&vw[64*LSTR + oct*8] = ea;
      *(f32x4*)&vw[64*LSTR + oct*8 + 4] = eb;
    }

    // stage D(r-1) into the other buffer (safe: last read of that buffer
    // was at iter r+1, separated by iter r+1's barrier)
    if (r > r0) *(f32x4*)&Dl[cur ^ 1][(t>>3)*LSTR + (t&7)*4] = pD;
    // prefetch D(r-2) and Y(r-1)
    if (r - 1 > r0) pD = *(const f32x4*)&gD[(size_t)(ro-2)*1024 + t*4];
    f32x4 nyA = z, nyB = z, n2A = z, n2B = z;
    if (r > r0) {
      const float* yb = YPTR(ro - 1, ss);
      nyA = *(const f32x4*)&yb[oct*8]; nyB = *(const f32x4*)&yb[oct*8 + 4];
      if (t < 4) { const float* yb2 = YPTR(ro - 1, 64);
        n2A = *(const f32x4*)&yb2[oct*8]; n2B = *(const f32x4*)&yb2[oct*8 + 4]; }
    }
    __syncthreads();

    if (r < r0 + BBWD) {
      if (ss >= 1) {
        f32x4 v0a = *(const f32x4*)&v0buf[cur][oct*8];
        f32x4 v0b = *(const f32x4*)&v0buf[cur][oct*8 + 4];
        float* dst = outg + ((size_t)r*64 + (size_t)(ss-1))*32 + oct*8;
        f32x4 o0 = {a0+v0a[0], a1+v0a[1], a2+v0a[2], a3+v0a[3]};
        f32x4 o1 = {a4+v0b[0], a5+v0b[1], a6+v0b[2], a7+v0b[3]};
        *(f32x4*)dst = o0;
        *(f32x4*)(dst + 4) = o1;
      } else if (t < 4) {
        float* dst = outg + ((size_t)r*64 + 63)*32 + oct*8;
        f32x4 o0 = {e0+a0, e1+a1, e2+a2, e3+a3};
        f32x4 o1 = {e4+a4, e5+a5, e6+a6, e7+a7};
        *(f32x4*)dst = o0;
        *(f32x4*)(dst + 4) = o1;
      }
    }

    yA = nyA; yB = nyB;
    if (t < 4) { y2A = n2A; y2B = n2B; }
  }
  #undef YPTR
}

extern "C" void kernel_launch(void* const* d_in, const int* in_sizes, int n_in,
                              void* d_out, int out_size, void* d_ws, size_t ws_size,
                              hipStream_t stream) {
  (void)in_sizes; (void)n_in; (void)out_size;
  const void* H = d_in[0];   // x_hessian_diags [R,32,32] fp32
  const void* G = d_in[1];   // x_grads         [R,1,32]  fp32
  const void* M = d_in[2];   // x_trans_mat     [32,32]   fp32
  const void* W = d_in[3];   // x_trans_prec    [32,32]   fp32
  const void* I = d_in[4];   // x_init_prec     [32,32]   fp32
  const void* E = d_in[5];   // epsx            [R,64,32] fp32
  float* out = (float*)d_out;  // [R,64,32] fp32 (reference output dtype)

  int* flag = (int*)d_ws;                         // dtype flag (first 256 B reserved)
  float* ws0 = (float*)((char*)d_ws + 256);
  size_t avail = (ws_size > 256) ? (ws_size - 256) : 0;

  // Per-row ws: Linv/Ye1 4KB + Ct/D 4KB + U/Y0 128B + Ye2 4KB = 12416 B.
  int nseg = 64;
  for (int cand = 1; cand <= 64; cand <<= 1) {
    size_t nrext = (size_t)(RTOT / cand) + WBWD;
    if (nrext * 12416 <= avail) { nseg = cand; break; }
  }
  const int segrows = RTOT / nseg;
  const size_t nrext_max = (size_t)segrows + WBWD;

  float* gLinv = ws0;                               // then Ye rows 0..31
  float* gCt  = ws0 + nrext_max * 1024;             // then D
  float* gU   = ws0 + nrext_max * 2048;             // then Y0
  float* gY2  = ws0 + nrext_max * 2080;             // Ye rows 32..63

  detect_kernel<<<1, 64, 0, stream>>>(W, flag);

  for (int s = 0; s < nseg; ++s) {
    int s0 = s * segrows;
    int s1ext = s0 + segrows + WBWD; if (s1ext > RTOT) s1ext = RTOT;
    int nr = s1ext - s0;
    int nfb = (nr + BFWD - 1) / BFWD;
    fwd_kernel<<<nfb, 64, 0, stream>>>(H, G, M, W, I, s0, flag, gLinv, gCt, gU);
    mid_kernel<<<nr, 256, 0, stream>>>(E, flag, gLinv, gCt, gU, gY2, s0);
    bwd_kernel<<<segrows / BBWD, 256, 0, stream>>>(gCt, gLinv, gY2, gU, out, s0);
  }
}

// Round 6
// 459.207 us; speedup vs baseline: 3.4854x; 1.2128x over previous
//
#include <hip/hip_runtime.h>
#include <stdint.h>

#define RTOT 8192
#define BFWD 4      // rows produced per forward block
#define WFWD 16     // forward warmup steps (24->16 THIS ROUND; absmax is the canary)
#define BBWD 32     // rows per backward block (256 blocks)
#define WBWD 16     // backward warmup steps (24->16)
#define LSTR 36     // LDS row stride in floats

typedef unsigned short u16;
typedef __attribute__((ext_vector_type(4))) float f32x4;
typedef __attribute__((ext_vector_type(8))) unsigned short u16x8;

__device__ __forceinline__ float bf2f(u16 u) { return __uint_as_float(((uint32_t)u) << 16); }
__device__ __forceinline__ float rdlane(float v, int l) {
  return __int_as_float(__builtin_amdgcn_readlane(__float_as_int(v), l));
}

// Dual-dtype input loaders. bf==true: bf16 container; bf==false: fp32 container.
__device__ __forceinline__ void load8(const void* p, size_t off, bool bf, float* o) {
  if (bf) {
    u16x8 v = *(const u16x8*)((const u16*)p + off);
    #pragma unroll
    for (int e = 0; e < 8; ++e) o[e] = bf2f(v[e]);
  } else {
    f32x4 a = *(const f32x4*)((const float*)p + off);
    f32x4 b = *(const f32x4*)((const float*)p + off + 4);
    o[0]=a[0]; o[1]=a[1]; o[2]=a[2]; o[3]=a[3];
    o[4]=b[0]; o[5]=b[1]; o[6]=b[2]; o[7]=b[3];
  }
}
__device__ __forceinline__ float load1(const void* p, size_t off, bool bf) {
  return bf ? bf2f(((const u16*)p)[off]) : ((const float*)p)[off];
}

// ======================= DTYPE DETECTOR =======================
__global__ void detect_kernel(const void* Wptr, int* flag) {
  if (threadIdx.x == 0) {
    const u16* w = (const u16*)Wptr;
    int ok = 1;
    const int pi[4] = {0, 0, 1, 2};
    const int pj[4] = {1, 2, 2, 3};
    #pragma unroll
    for (int p = 0; p < 4; ++p)
      ok &= (w[pi[p]*32 + pj[p]] == w[pj[p]*32 + pi[p]]) ? 1 : 0;
    *flag = ok;   // 1 = bf16 container, 0 = fp32 container
  }
}

// ============================ FORWARD ============================
// (structure unchanged from round 4 — proven; only WFWD shrank)
__global__ __launch_bounds__(64, 2) void fwd_kernel(
    const void* __restrict__ Hg, const void* __restrict__ Gg,
    const void* __restrict__ Mg, const void* __restrict__ Wg,
    const void* __restrict__ Ig, int s0, const int* __restrict__ flag,
    float* __restrict__ gLinv, float* __restrict__ gCt, float* __restrict__ gU)
{
  __shared__ __align__(16) float ldsCt[32*LSTR];
  __shared__ __align__(16) float ldsLinv[32*LSTR];
  __shared__ float ldsU[32];

  const bool bf = (*flag != 0);
  const int lane = threadIdx.x & 63;
  const int il = lane & 31;
  const bool lo = (lane < 32);
  const int hoff = (lane >> 5) * 16;

  float wrow[32], mrow[32];
  #pragma unroll
  for (int c = 0; c < 4; ++c) {
    float wt[8], mt[8];
    load8(Wg, il*32 + c*8, bf, wt);
    load8(Mg, il*32 + c*8, bf, mt);
    #pragma unroll
    for (int e = 0; e < 8; ++e) {
      wrow[c*8+e] = wt[e]; mrow[c*8+e] = mt[e];
      ldsCt[il*LSTR + c*8+e] = mt[e];
    }
  }
  __syncthreads();

  #pragma unroll 4
  for (int m = 0; m < 32; ++m) {
    float acc = 0.0f;
    #pragma unroll
    for (int c = 0; c < 8; ++c) {
      f32x4 q = *(const f32x4*)&ldsCt[m*LSTR + c*4];
      acc = fmaf(q[0], wrow[c*4+0], acc); acc = fmaf(q[1], wrow[c*4+1], acc);
      acc = fmaf(q[2], wrow[c*4+2], acc); acc = fmaf(q[3], wrow[c*4+3], acc);
    }
    ldsLinv[m*LSTR + il] = acc;
  }
  __syncthreads();
  #pragma unroll 4
  for (int m = 0; m < 32; ++m) {
    float acc = 0.0f;
    #pragma unroll
    for (int c = 0; c < 8; ++c) {
      f32x4 q = *(const f32x4*)&ldsLinv[m*LSTR + c*4];
      acc = fmaf(q[0], mrow[c*4+0], acc); acc = fmaf(q[1], mrow[c*4+1], acc);
      acc = fmaf(q[2], mrow[c*4+2], acc); acc = fmaf(q[3], mrow[c*4+3], acc);
    }
    ldsCt[m*LSTR + il] = acc;
  }
  __syncthreads();

  float mtpcol[32];
  #pragma unroll
  for (int t = 0; t < 32; ++t) mtpcol[t] = ldsLinv[t*LSTR + il];
  float k0h[16];
  #pragma unroll
  for (int c = 0; c < 16; ++c) {
    float a = wrow[c]      + ldsCt[il*LSTR + c];
    float b = wrow[c + 16] + ldsCt[il*LSTR + 16 + c];
    k0h[c] = lo ? a : b;
  }
  __syncthreads();

  #pragma unroll
  for (int k = 0; k < 32; ++k) ldsCt[il*LSTR + k] = 0.0f;
  if (lo) ldsU[il] = 0.0f;
  __syncthreads();

  const int r0 = s0 + blockIdx.x * BFWD;
  const int rw0 = (r0 >= WFWD) ? (r0 - WFWD) : 0;
  const int rend = r0 + BFWD;

  float hcur[16];
  #pragma unroll
  for (int c = 0; c < 2; ++c)
    load8(Hg, (size_t)rw0*1024 + il*32 + hoff + c*8, bf, &hcur[c*8]);
  float gv = load1(Gg, (size_t)rw0*32 + il, bf);

  for (int r = rw0; r < rend; ++r) {
    int rn = (r + 1 < RTOT) ? (r + 1) : r;
    float hnext[16];
    #pragma unroll
    for (int c = 0; c < 2; ++c)
      load8(Hg, (size_t)rn*1024 + il*32 + hoff + c*8, bf, &hnext[c*8]);
    float gvn = load1(Gg, (size_t)rn*32 + il, bf);

    float sv[16];
    if (r == 0) {
      #pragma unroll
      for (int c = 0; c < 2; ++c) {
        float it[8], wt[8];
        load8(Ig, il*32 + hoff + c*8, bf, it);
        load8(Wg, il*32 + hoff + c*8, bf, wt);
        #pragma unroll
        for (int e = 0; e < 8; ++e)
          sv[c*8+e] = hcur[c*8+e] + it[e] + (k0h[c*8+e] - wt[e]);
      }
    } else if (r == RTOT - 1) {
      #pragma unroll
      for (int c = 0; c < 2; ++c) {
        float wt[8];
        load8(Wg, il*32 + hoff + c*8, bf, wt);
        #pragma unroll
        for (int e = 0; e < 8; ++e) sv[c*8+e] = hcur[c*8+e] + wt[e];
      }
    } else {
      #pragma unroll
      for (int k = 0; k < 16; ++k) sv[k] = hcur[k] + k0h[k];
    }

    float y = gv;
    #pragma unroll 4
    for (int m = 0; m < 32; ++m) {
      float cm = ldsCt[m*LSTR + il];
      y = fmaf(ldsU[m], cm, y);
      #pragma unroll
      for (int c = 0; c < 4; ++c) {
        f32x4 q = *(const f32x4*)&ldsCt[m*LSTR + hoff + c*4];
        sv[c*4+0] = fmaf(-cm, q[0], sv[c*4+0]);
        sv[c*4+1] = fmaf(-cm, q[1], sv[c*4+1]);
        sv[c*4+2] = fmaf(-cm, q[2], sv[c*4+2]);
        sv[c*4+3] = fmaf(-cm, q[3], sv[c*4+3]);
      }
    }

    float v[32];
    #pragma unroll
    for (int c = 0; c < 16; ++c) {
      float o = __shfl_xor(sv[c], 32, 64);
      v[c]      = lo ? sv[c] : mtpcol[c];
      v[c + 16] = lo ? o     : mtpcol[c + 16];
    }

    float un = 0.0f;
    float yr = y;
    if (r < r0) {
      #pragma unroll
      for (int j = 0; j < 32; ++j) {
        float dj = fmaxf(rdlane(v[j], j), 1e-12f);
        float rs = __builtin_amdgcn_rsqf(dj);
        float a = v[j] * rs;
        v[j] = a;
        float uj = rdlane(yr, j) * rs;
        yr = fmaf(-a, uj, yr);
        if (il == j) un = uj;
        #pragma unroll
        for (int k = j + 1; k < 32; ++k) {
          float bk = rdlane(v[j], k);
          v[k] = fmaf(-a, bk, v[k]);
        }
      }
    } else {
      float w[32];
      #pragma unroll
      for (int i = 0; i < 32; ++i) w[i] = (lo && il == i) ? 1.0f : 0.0f;
      #pragma unroll
      for (int j = 0; j < 32; ++j) {
        float dj = fmaxf(rdlane(v[j], j), 1e-12f);
        float rs = __builtin_amdgcn_rsqf(dj);
        float a = v[j] * rs;
        v[j] = a;
        float b = w[j] * rs;
        w[j] = b;
        float uj = rdlane(yr, j) * rs;
        yr = fmaf(-a, uj, yr);
        if (il == j) un = uj;
        #pragma unroll
        for (int k = j + 1; k < 32; ++k) {
          float bk = rdlane(v[j], k);
          v[k] = fmaf(-a, bk, v[k]);
          w[k] = fmaf(-b, bk, w[k]);
        }
      }
      if (lo) {
        #pragma unroll
        for (int i = 0; i < 32; ++i) ldsLinv[i*LSTR + il] = w[i];
      }
    }

    if (!lo) {
      #pragma unroll
      for (int m = 0; m < 32; ++m) ldsCt[m*LSTR + il] = v[m];
    } else {
      ldsU[il] = un;
    }

    if (r >= r0) {
      __syncthreads();
      size_t ro = (size_t)(r - s0);
      #pragma unroll
      for (int c = 0; c < 4; ++c) {
        int f = lane*16 + c*4;
        int mm = f >> 5, kk = f & 31;
        *(f32x4*)&gLinv[ro*1024 + f] = *(const f32x4*)&ldsLinv[mm*LSTR + kk];
        *(f32x4*)&gCt [ro*1024 + f] = *(const f32x4*)&ldsCt [mm*LSTR + kk];
      }
      if (lo) gU[ro*32 + il] = un;
    }

    #pragma unroll
    for (int e = 0; e < 16; ++e) hcur[e] = hnext[e];
    gv = gvn;
  }
}

// ============================ MID ============================
// (unchanged from round 5) Fully parallel per-row transform:
//   Ye = eps*Linv, Y0 = u*Linv, D = Ct^T*Linv  (in-place over ws buffers)
__global__ __launch_bounds__(256, 2) void mid_kernel(
    const void* __restrict__ Eg, const int* __restrict__ flag,
    float* __restrict__ gLinv, float* __restrict__ gCt,
    float* __restrict__ gU, float* __restrict__ gY2, int s0)
{
  __shared__ __align__(16) float Li[32*LSTR];
  __shared__ __align__(16) float Ct_[32*LSTR];
  __shared__ float Ut[32];

  const bool bf = (*flag != 0);
  const int t = threadIdx.x;
  const size_t ro = blockIdx.x;
  const size_t r = (size_t)s0 + ro;

  {
    int mm = t >> 3, kk = (t & 7) * 4;
    *(f32x4*)&Li[mm*LSTR + kk]  = *(const f32x4*)&gLinv[ro*1024 + t*4];
    *(f32x4*)&Ct_[mm*LSTR + kk] = *(const f32x4*)&gCt [ro*1024 + t*4];
    if (t < 32) Ut[t] = gU[ro*32 + t];
  }
  __syncthreads();

  {
    int s = t >> 2, oct = t & 3;
    float er[32];
    #pragma unroll
    for (int c = 0; c < 4; ++c) load8(Eg, (r*64 + (size_t)s)*32 + c*8, bf, &er[c*8]);
    float a0=0,a1=0,a2=0,a3=0,a4=0,a5=0,a6=0,a7=0;
    #pragma unroll 4
    for (int k = 0; k < 32; ++k) {
      f32x4 b  = *(const f32x4*)&Li[k*LSTR + oct*8];
      f32x4 b2 = *(const f32x4*)&Li[k*LSTR + oct*8 + 4];
      float ek = er[k];
      a0=fmaf(ek,b[0],a0);  a1=fmaf(ek,b[1],a1);
      a2=fmaf(ek,b[2],a2);  a3=fmaf(ek,b[3],a3);
      a4=fmaf(ek,b2[0],a4); a5=fmaf(ek,b2[1],a5);
      a6=fmaf(ek,b2[2],a6); a7=fmaf(ek,b2[3],a7);
    }
    float* dst = (s < 32) ? (gLinv + ro*1024 + (size_t)s*32)
                          : (gY2  + ro*1024 + (size_t)(s-32)*32);
    f32x4 va = {a0,a1,a2,a3}, vb = {a4,a5,a6,a7};
    *(f32x4*)&dst[oct*8] = va;
    *(f32x4*)&dst[oct*8 + 4] = vb;
  }

  {
    int m = t >> 3, jo = t & 7;
    float d0=0,d1=0,d2=0,d3=0;
    #pragma unroll 4
    for (int k = 0; k < 32; ++k) {
      float cv = Ct_[k*LSTR + m];
      f32x4 b = *(const f32x4*)&Li[k*LSTR + jo*4];
      d0=fmaf(cv,b[0],d0); d1=fmaf(cv,b[1],d1);
      d2=fmaf(cv,b[2],d2); d3=fmaf(cv,b[3],d3);
    }
    f32x4 dv = {d0,d1,d2,d3};
    *(f32x4*)&gCt[ro*1024 + (size_t)m*32 + jo*4] = dv;
  }

  if (t < 32) {
    float a = 0.0f;
    #pragma unroll
    for (int k = 0; k < 32; ++k) a = fmaf(Ut[k], Li[k*LSTR + t], a);
    gU[ro*32 + t] = a;
  }
}

// ============================ BACKWARD ============================
// vw'[s] = Y[s] + vw[s]*D, one matmul + one barrier per step.
// NEW: register-reuse pairing — thread (pr = t>>3, o = t&7) owns rows
// {pr, pr+32} x cols [o*4, o*4+4): each D read from LDS feeds TWO rows.
// Threads t<8 (pair 0) additionally handle row 64 (masked re-read of D).
// Per-element FMA order (k ascending) identical to round 5 -> bit-exact.
__global__ __launch_bounds__(256, 1) void bwd_kernel(
    const float* __restrict__ gD,   // = gCt region (D after mid)
    const float* __restrict__ gY1,  // = gLinv region (Ye rows 0..31)
    const float* __restrict__ gY2,  // Ye rows 32..63
    const float* __restrict__ gY0,  // = gU region (Y0)
    float* __restrict__ outg, int s0)
{
  __shared__ __align__(16) float vw[65*LSTR];
  __shared__ __align__(16) float Dl[2][32*LSTR];
  __shared__ __align__(16) float v0buf[2][32];

  const int t = threadIdx.x;
  const int pr = t >> 3;          // pair index 0..31: rows pr and pr+32
  const int o  = t & 7;           // 4-col group
  const int rowA = pr, rowB = pr + 32;
  const bool x64 = (t < 8);       // pair 0 also handles row 64
  const int r0 = s0 + blockIdx.x * BBWD;
  int re = r0 + BBWD - 1 + WBWD; if (re > RTOT - 1) re = RTOT - 1;

  for (int i = t; i < 65*LSTR; i += 256) vw[i] = 0.0f;

  #define YPTR(RO_, S_) \
    ((S_) == 0  ? (gY0 + (size_t)(RO_)*32) : \
     (S_) <= 32 ? (gY1 + (size_t)(RO_)*1024 + (size_t)((S_)-1)*32) \
                : (gY2 + (size_t)(RO_)*1024 + (size_t)((S_)-33)*32))

  f32x4 z = {0,0,0,0};
  // prologue for r = re
  const int reo = re - s0;
  f32x4 pD = *(const f32x4*)&gD[(size_t)reo*1024 + t*4];
  f32x4 yA, yB, yC = z;
  yA = *(const f32x4*)&(YPTR(reo, rowA))[o*4];
  yB = *(const f32x4*)&(YPTR(reo, rowB))[o*4];
  if (x64) yC = *(const f32x4*)&(YPTR(reo, 64))[o*4];
  *(f32x4*)&Dl[re & 1][pr*LSTR + o*4] = pD;
  if (re > r0) pD = *(const f32x4*)&gD[(size_t)(reo-1)*1024 + t*4];
  __syncthreads();

  for (int r = re; r >= r0; --r) {
    const int cur = r & 1;
    const int ro = r - s0;

    // load both vw rows into registers
    float vrA[32], vrB[32];
    #pragma unroll
    for (int c = 0; c < 8; ++c) {
      f32x4 qa = *(const f32x4*)&vw[rowA*LSTR + c*4];
      f32x4 qb = *(const f32x4*)&vw[rowB*LSTR + c*4];
      vrA[c*4+0]=qa[0]; vrA[c*4+1]=qa[1]; vrA[c*4+2]=qa[2]; vrA[c*4+3]=qa[3];
      vrB[c*4+0]=qb[0]; vrB[c*4+1]=qb[1]; vrB[c*4+2]=qb[2]; vrB[c*4+3]=qb[3];
    }

    float a0=yA[0],a1=yA[1],a2=yA[2],a3=yA[3];
    float b0=yB[0],b1=yB[1],b2=yB[2],b3=yB[3];
    #pragma unroll 4
    for (int k = 0; k < 32; ++k) {
      f32x4 d = *(const f32x4*)&Dl[cur][k*LSTR + o*4];
      float xa = vrA[k], xb = vrB[k];
      a0=fmaf(xa,d[0],a0); a1=fmaf(xa,d[1],a1);
      a2=fmaf(xa,d[2],a2); a3=fmaf(xa,d[3],a3);
      b0=fmaf(xb,d[0],b0); b1=fmaf(xb,d[1],b1);
      b2=fmaf(xb,d[2],b2); b3=fmaf(xb,d[3],b3);
    }
    f32x4 va = {a0,a1,a2,a3}, vb = {b0,b1,b2,b3};
    *(f32x4*)&vw[rowA*LSTR + o*4] = va;
    *(f32x4*)&vw[rowB*LSTR + o*4] = vb;

    // row 64 + v0 broadcast on pair 0 (masked; D re-read from LDS)
    float c0=0,c1=0,c2=0,c3=0;
    if (x64) {
      *(f32x4*)&v0buf[cur][o*4] = va;   // rowA == 0 here
      float vrC[32];
      #pragma unroll
      for (int c = 0; c < 8; ++c) {
        f32x4 q = *(const f32x4*)&vw[64*LSTR + c*4];
        vrC[c*4+0]=q[0]; vrC[c*4+1]=q[1]; vrC[c*4+2]=q[2]; vrC[c*4+3]=q[3];
      }
      c0=yC[0]; c1=yC[1]; c2=yC[2]; c3=yC[3];
      #pragma unroll 4
      for (int k = 0; k < 32; ++k) {
        f32x4 d = *(const f32x4*)&Dl[cur][k*LSTR + o*4];
        float xc = vrC[k];
        c0=fmaf(xc,d[0],c0); c1=fmaf(xc,d[1],c1);
        c2=fmaf(xc,d[2],c2); c3=fmaf(xc,d[3],c3);
      }
      f32x4 vc = {c0,c1,c2,c3};
      *(f32x4*)&vw[64*LSTR + o*4] = vc;
    }

    // stage D(r-1); prefetch D(r-2), Y(r-1)
    if (r > r0) *(f32x4*)&Dl[cur ^ 1][pr*LSTR + o*4] = pD;
    if (r - 1 > r0) pD = *(const f32x4*)&gD[(size_t)(ro-2)*1024 + t*4];
    f32x4 nyA = z, nyB = z, nyC = z;
    if (r > r0) {
      nyA = *(const f32x4*)&(YPTR(ro - 1, rowA))[o*4];
      nyB = *(const f32x4*)&(YPTR(ro - 1, rowB))[o*4];
      if (x64) nyC = *(const f32x4*)&(YPTR(ro - 1, 64))[o*4];
    }
    __syncthreads();

    if (r < r0 + BBWD) {
      f32x4 v0 = *(const f32x4*)&v0buf[cur][o*4];
      if (pr >= 1) {   // rowA -> out row pr-1
        float* dst = outg + ((size_t)r*64 + (size_t)(pr-1))*32 + o*4;
        f32x4 oo = {a0+v0[0], a1+v0[1], a2+v0[2], a3+v0[3]};
        *(f32x4*)dst = oo;
      }
      {                // rowB -> out row pr+31
        float* dst = outg + ((size_t)r*64 + (size_t)(pr+31))*32 + o*4;
        f32x4 oo = {b0+v0[0], b1+v0[1], b2+v0[2], b3+v0[3]};
        *(f32x4*)dst = oo;
      }
      if (x64) {       // row 64 -> out row 63
        float* dst = outg + ((size_t)r*64 + 63)*32 + o*4;
        f32x4 oo = {c0+v0[0], c1+v0[1], c2+v0[2], c3+v0[3]};
        *(f32x4*)dst = oo;
      }
    }

    yA = nyA; yB = nyB;
    if (x64) yC = nyC;
  }
  #undef YPTR
}

extern "C" void kernel_launch(void* const* d_in, const int* in_sizes, int n_in,
                              void* d_out, int out_size, void* d_ws, size_t ws_size,
                              hipStream_t stream) {
  (void)in_sizes; (void)n_in; (void)out_size;
  const void* H = d_in[0];   // x_hessian_diags [R,32,32]
  const void* G = d_in[1];   // x_grads         [R,1,32]
  const void* M = d_in[2];   // x_trans_mat     [32,32]
  const void* W = d_in[3];   // x_trans_prec    [32,32]
  const void* I = d_in[4];   // x_init_prec     [32,32]
  const void* E = d_in[5];   // epsx            [R,64,32]
  float* out = (float*)d_out;  // [R,64,32] fp32

  int* flag = (int*)d_ws;                         // dtype flag (first 256 B reserved)
  float* ws0 = (float*)((char*)d_ws + 256);
  size_t avail = (ws_size > 256) ? (ws_size - 256) : 0;

  // Per-row ws: Linv/Ye1 4KB + Ct/D 4KB + U/Y0 128B + Ye2 4KB = 12416 B.
  int nseg = 64;
  for (int cand = 1; cand <= 64; cand <<= 1) {
    size_t nrext = (size_t)(RTOT / cand) + WBWD;
    if (nrext * 12416 <= avail) { nseg = cand; break; }
  }
  const int segrows = RTOT / nseg;
  const size_t nrext_max = (size_t)segrows + WBWD;

  float* gLinv = ws0;                               // then Ye rows 0..31
  float* gCt  = ws0 + nrext_max * 1024;             // then D
  float* gU   = ws0 + nrext_max * 2048;             // then Y0
  float* gY2  = ws0 + nrext_max * 2080;             // Ye rows 32..63

  detect_kernel<<<1, 64, 0, stream>>>(W, flag);

  for (int s = 0; s < nseg; ++s) {
    int s0 = s * segrows;
    int s1ext = s0 + segrows + WBWD; if (s1ext > RTOT) s1ext = RTOT;
    int nr = s1ext - s0;
    int nfb = (nr + BFWD - 1) / BFWD;
    fwd_kernel<<<nfb, 64, 0, stream>>>(H, G, M, W, I, s0, flag, gLinv, gCt, gU);
    mid_kernel<<<nr, 256, 0, stream>>>(E, flag, gLinv, gCt, gU, gY2, s0);
    bwd_kernel<<<segrows / BBWD, 256, 0, stream>>>(gCt, gLinv, gY2, gU, out, s0);
  }
}

// Round 7
// 416.263 us; speedup vs baseline: 3.8450x; 1.1032x over previous
//
#include <hip/hip_runtime.h>
#include <stdint.h>

#define RTOT 8192
#define BFWD 4      // rows produced per forward block
#define WFWD 12     // forward warmup steps (16->12 THIS ROUND; absmax is the canary)
#define BBWD 16     // rows per backward block (32->16: 512 blocks, 2 blocks/CU)
#define WBWD 16     // backward warmup steps (validated at 16)
#define LSTR 36     // LDS row stride in floats

typedef unsigned short u16;
typedef __attribute__((ext_vector_type(4))) float f32x4;
typedef __attribute__((ext_vector_type(8))) unsigned short u16x8;

__device__ __forceinline__ float bf2f(u16 u) { return __uint_as_float(((uint32_t)u) << 16); }
__device__ __forceinline__ float rdlane(float v, int l) {
  return __int_as_float(__builtin_amdgcn_readlane(__float_as_int(v), l));
}

// Dual-dtype input loaders. bf==true: bf16 container; bf==false: fp32 container.
__device__ __forceinline__ void load8(const void* p, size_t off, bool bf, float* o) {
  if (bf) {
    u16x8 v = *(const u16x8*)((const u16*)p + off);
    #pragma unroll
    for (int e = 0; e < 8; ++e) o[e] = bf2f(v[e]);
  } else {
    f32x4 a = *(const f32x4*)((const float*)p + off);
    f32x4 b = *(const f32x4*)((const float*)p + off + 4);
    o[0]=a[0]; o[1]=a[1]; o[2]=a[2]; o[3]=a[3];
    o[4]=b[0]; o[5]=b[1]; o[6]=b[2]; o[7]=b[3];
  }
}
__device__ __forceinline__ float load1(const void* p, size_t off, bool bf) {
  return bf ? bf2f(((const u16*)p)[off]) : ((const float*)p)[off];
}

// ======================= DTYPE DETECTOR =======================
__global__ void detect_kernel(const void* Wptr, int* flag) {
  if (threadIdx.x == 0) {
    const u16* w = (const u16*)Wptr;
    int ok = 1;
    const int pi[4] = {0, 0, 1, 2};
    const int pj[4] = {1, 2, 2, 3};
    #pragma unroll
    for (int p = 0; p < 4; ++p)
      ok &= (w[pi[p]*32 + pj[p]] == w[pj[p]*32 + pi[p]]) ? 1 : 0;
    *flag = ok;   // 1 = bf16 container, 0 = fp32 container
  }
}

// ============================ FORWARD ============================
// (structure unchanged from round 4 — proven; only WFWD shrank)
__global__ __launch_bounds__(64, 2) void fwd_kernel(
    const void* __restrict__ Hg, const void* __restrict__ Gg,
    const void* __restrict__ Mg, const void* __restrict__ Wg,
    const void* __restrict__ Ig, int s0, const int* __restrict__ flag,
    float* __restrict__ gLinv, float* __restrict__ gCt, float* __restrict__ gU)
{
  __shared__ __align__(16) float ldsCt[32*LSTR];
  __shared__ __align__(16) float ldsLinv[32*LSTR];
  __shared__ float ldsU[32];

  const bool bf = (*flag != 0);
  const int lane = threadIdx.x & 63;
  const int il = lane & 31;
  const bool lo = (lane < 32);
  const int hoff = (lane >> 5) * 16;

  float wrow[32], mrow[32];
  #pragma unroll
  for (int c = 0; c < 4; ++c) {
    float wt[8], mt[8];
    load8(Wg, il*32 + c*8, bf, wt);
    load8(Mg, il*32 + c*8, bf, mt);
    #pragma unroll
    for (int e = 0; e < 8; ++e) {
      wrow[c*8+e] = wt[e]; mrow[c*8+e] = mt[e];
      ldsCt[il*LSTR + c*8+e] = mt[e];
    }
  }
  __syncthreads();

  #pragma unroll 4
  for (int m = 0; m < 32; ++m) {
    float acc = 0.0f;
    #pragma unroll
    for (int c = 0; c < 8; ++c) {
      f32x4 q = *(const f32x4*)&ldsCt[m*LSTR + c*4];
      acc = fmaf(q[0], wrow[c*4+0], acc); acc = fmaf(q[1], wrow[c*4+1], acc);
      acc = fmaf(q[2], wrow[c*4+2], acc); acc = fmaf(q[3], wrow[c*4+3], acc);
    }
    ldsLinv[m*LSTR + il] = acc;
  }
  __syncthreads();
  #pragma unroll 4
  for (int m = 0; m < 32; ++m) {
    float acc = 0.0f;
    #pragma unroll
    for (int c = 0; c < 8; ++c) {
      f32x4 q = *(const f32x4*)&ldsLinv[m*LSTR + c*4];
      acc = fmaf(q[0], mrow[c*4+0], acc); acc = fmaf(q[1], mrow[c*4+1], acc);
      acc = fmaf(q[2], mrow[c*4+2], acc); acc = fmaf(q[3], mrow[c*4+3], acc);
    }
    ldsCt[m*LSTR + il] = acc;
  }
  __syncthreads();

  float mtpcol[32];
  #pragma unroll
  for (int t = 0; t < 32; ++t) mtpcol[t] = ldsLinv[t*LSTR + il];
  float k0h[16];
  #pragma unroll
  for (int c = 0; c < 16; ++c) {
    float a = wrow[c]      + ldsCt[il*LSTR + c];
    float b = wrow[c + 16] + ldsCt[il*LSTR + 16 + c];
    k0h[c] = lo ? a : b;
  }
  __syncthreads();

  #pragma unroll
  for (int k = 0; k < 32; ++k) ldsCt[il*LSTR + k] = 0.0f;
  if (lo) ldsU[il] = 0.0f;
  __syncthreads();

  const int r0 = s0 + blockIdx.x * BFWD;
  const int rw0 = (r0 >= WFWD) ? (r0 - WFWD) : 0;
  const int rend = r0 + BFWD;

  float hcur[16];
  #pragma unroll
  for (int c = 0; c < 2; ++c)
    load8(Hg, (size_t)rw0*1024 + il*32 + hoff + c*8, bf, &hcur[c*8]);
  float gv = load1(Gg, (size_t)rw0*32 + il, bf);

  for (int r = rw0; r < rend; ++r) {
    int rn = (r + 1 < RTOT) ? (r + 1) : r;
    float hnext[16];
    #pragma unroll
    for (int c = 0; c < 2; ++c)
      load8(Hg, (size_t)rn*1024 + il*32 + hoff + c*8, bf, &hnext[c*8]);
    float gvn = load1(Gg, (size_t)rn*32 + il, bf);

    float sv[16];
    if (r == 0) {
      #pragma unroll
      for (int c = 0; c < 2; ++c) {
        float it[8], wt[8];
        load8(Ig, il*32 + hoff + c*8, bf, it);
        load8(Wg, il*32 + hoff + c*8, bf, wt);
        #pragma unroll
        for (int e = 0; e < 8; ++e)
          sv[c*8+e] = hcur[c*8+e] + it[e] + (k0h[c*8+e] - wt[e]);
      }
    } else if (r == RTOT - 1) {
      #pragma unroll
      for (int c = 0; c < 2; ++c) {
        float wt[8];
        load8(Wg, il*32 + hoff + c*8, bf, wt);
        #pragma unroll
        for (int e = 0; e < 8; ++e) sv[c*8+e] = hcur[c*8+e] + wt[e];
      }
    } else {
      #pragma unroll
      for (int k = 0; k < 16; ++k) sv[k] = hcur[k] + k0h[k];
    }

    float y = gv;
    #pragma unroll 4
    for (int m = 0; m < 32; ++m) {
      float cm = ldsCt[m*LSTR + il];
      y = fmaf(ldsU[m], cm, y);
      #pragma unroll
      for (int c = 0; c < 4; ++c) {
        f32x4 q = *(const f32x4*)&ldsCt[m*LSTR + hoff + c*4];
        sv[c*4+0] = fmaf(-cm, q[0], sv[c*4+0]);
        sv[c*4+1] = fmaf(-cm, q[1], sv[c*4+1]);
        sv[c*4+2] = fmaf(-cm, q[2], sv[c*4+2]);
        sv[c*4+3] = fmaf(-cm, q[3], sv[c*4+3]);
      }
    }

    float v[32];
    #pragma unroll
    for (int c = 0; c < 16; ++c) {
      float o = __shfl_xor(sv[c], 32, 64);
      v[c]      = lo ? sv[c] : mtpcol[c];
      v[c + 16] = lo ? o     : mtpcol[c + 16];
    }

    float un = 0.0f;
    float yr = y;
    if (r < r0) {
      #pragma unroll
      for (int j = 0; j < 32; ++j) {
        float dj = fmaxf(rdlane(v[j], j), 1e-12f);
        float rs = __builtin_amdgcn_rsqf(dj);
        float a = v[j] * rs;
        v[j] = a;
        float uj = rdlane(yr, j) * rs;
        yr = fmaf(-a, uj, yr);
        if (il == j) un = uj;
        #pragma unroll
        for (int k = j + 1; k < 32; ++k) {
          float bk = rdlane(v[j], k);
          v[k] = fmaf(-a, bk, v[k]);
        }
      }
    } else {
      float w[32];
      #pragma unroll
      for (int i = 0; i < 32; ++i) w[i] = (lo && il == i) ? 1.0f : 0.0f;
      #pragma unroll
      for (int j = 0; j < 32; ++j) {
        float dj = fmaxf(rdlane(v[j], j), 1e-12f);
        float rs = __builtin_amdgcn_rsqf(dj);
        float a = v[j] * rs;
        v[j] = a;
        float b = w[j] * rs;
        w[j] = b;
        float uj = rdlane(yr, j) * rs;
        yr = fmaf(-a, uj, yr);
        if (il == j) un = uj;
        #pragma unroll
        for (int k = j + 1; k < 32; ++k) {
          float bk = rdlane(v[j], k);
          v[k] = fmaf(-a, bk, v[k]);
          w[k] = fmaf(-b, bk, w[k]);
        }
      }
      if (lo) {
        #pragma unroll
        for (int i = 0; i < 32; ++i) ldsLinv[i*LSTR + il] = w[i];
      }
    }

    if (!lo) {
      #pragma unroll
      for (int m = 0; m < 32; ++m) ldsCt[m*LSTR + il] = v[m];
    } else {
      ldsU[il] = un;
    }

    if (r >= r0) {
      __syncthreads();
      size_t ro = (size_t)(r - s0);
      #pragma unroll
      for (int c = 0; c < 4; ++c) {
        int f = lane*16 + c*4;
        int mm = f >> 5, kk = f & 31;
        *(f32x4*)&gLinv[ro*1024 + f] = *(const f32x4*)&ldsLinv[mm*LSTR + kk];
        *(f32x4*)&gCt [ro*1024 + f] = *(const f32x4*)&ldsCt [mm*LSTR + kk];
      }
      if (lo) gU[ro*32 + il] = un;
    }

    #pragma unroll
    for (int e = 0; e < 16; ++e) hcur[e] = hnext[e];
    gv = gvn;
  }
}

// ============================ MID ============================
// (unchanged) Fully parallel per-row transform:
//   Ye = eps*Linv, Y0 = u*Linv, D = Ct^T*Linv  (in-place over ws buffers)
__global__ __launch_bounds__(256, 2) void mid_kernel(
    const void* __restrict__ Eg, const int* __restrict__ flag,
    float* __restrict__ gLinv, float* __restrict__ gCt,
    float* __restrict__ gU, float* __restrict__ gY2, int s0)
{
  __shared__ __align__(16) float Li[32*LSTR];
  __shared__ __align__(16) float Ct_[32*LSTR];
  __shared__ float Ut[32];

  const bool bf = (*flag != 0);
  const int t = threadIdx.x;
  const size_t ro = blockIdx.x;
  const size_t r = (size_t)s0 + ro;

  {
    int mm = t >> 3, kk = (t & 7) * 4;
    *(f32x4*)&Li[mm*LSTR + kk]  = *(const f32x4*)&gLinv[ro*1024 + t*4];
    *(f32x4*)&Ct_[mm*LSTR + kk] = *(const f32x4*)&gCt [ro*1024 + t*4];
    if (t < 32) Ut[t] = gU[ro*32 + t];
  }
  __syncthreads();

  {
    int s = t >> 2, oct = t & 3;
    float er[32];
    #pragma unroll
    for (int c = 0; c < 4; ++c) load8(Eg, (r*64 + (size_t)s)*32 + c*8, bf, &er[c*8]);
    float a0=0,a1=0,a2=0,a3=0,a4=0,a5=0,a6=0,a7=0;
    #pragma unroll 4
    for (int k = 0; k < 32; ++k) {
      f32x4 b  = *(const f32x4*)&Li[k*LSTR + oct*8];
      f32x4 b2 = *(const f32x4*)&Li[k*LSTR + oct*8 + 4];
      float ek = er[k];
      a0=fmaf(ek,b[0],a0);  a1=fmaf(ek,b[1],a1);
      a2=fmaf(ek,b[2],a2);  a3=fmaf(ek,b[3],a3);
      a4=fmaf(ek,b2[0],a4); a5=fmaf(ek,b2[1],a5);
      a6=fmaf(ek,b2[2],a6); a7=fmaf(ek,b2[3],a7);
    }
    float* dst = (s < 32) ? (gLinv + ro*1024 + (size_t)s*32)
                          : (gY2  + ro*1024 + (size_t)(s-32)*32);
    f32x4 va = {a0,a1,a2,a3}, vb = {a4,a5,a6,a7};
    *(f32x4*)&dst[oct*8] = va;
    *(f32x4*)&dst[oct*8 + 4] = vb;
  }

  {
    int m = t >> 3, jo = t & 7;
    float d0=0,d1=0,d2=0,d3=0;
    #pragma unroll 4
    for (int k = 0; k < 32; ++k) {
      float cv = Ct_[k*LSTR + m];
      f32x4 b = *(const f32x4*)&Li[k*LSTR + jo*4];
      d0=fmaf(cv,b[0],d0); d1=fmaf(cv,b[1],d1);
      d2=fmaf(cv,b[2],d2); d3=fmaf(cv,b[3],d3);
    }
    f32x4 dv = {d0,d1,d2,d3};
    *(f32x4*)&gCt[ro*1024 + (size_t)m*32 + jo*4] = dv;
  }

  if (t < 32) {
    float a = 0.0f;
    #pragma unroll
    for (int k = 0; k < 32; ++k) a = fmaf(Ut[k], Li[k*LSTR + t], a);
    gU[ro*32 + t] = a;
  }
}

// ============================ BACKWARD ============================
// vw'[s] = Y[s] + vw[s]*D, one matmul + one barrier per step.
// Register-reuse pairing: thread (pr = t>>3, o = t&7) owns rows {pr, pr+32}
// x cols [o*4, o*4+4); pair 0 (t<8) also handles row 64.
// THIS ROUND: (a) prefetch issued at TOP of loop so the matmul covers the
// global-load latency before the barrier's vmcnt(0) drain; (b) BBWD=16 +
// launch_bounds(256,2): 2 blocks/CU so one block computes while the other
// sits at its barrier. Per-row FMA order unchanged (k ascending).
__global__ __launch_bounds__(256, 2) void bwd_kernel(
    const float* __restrict__ gD,   // = gCt region (D after mid)
    const float* __restrict__ gY1,  // = gLinv region (Ye rows 0..31)
    const float* __restrict__ gY2,  // Ye rows 32..63
    const float* __restrict__ gY0,  // = gU region (Y0)
    float* __restrict__ outg, int s0)
{
  __shared__ __align__(16) float vw[65*LSTR];
  __shared__ __align__(16) float Dl[2][32*LSTR];
  __shared__ __align__(16) float v0buf[2][32];

  const int t = threadIdx.x;
  const int pr = t >> 3;          // pair index 0..31: rows pr and pr+32
  const int o  = t & 7;           // 4-col group
  const int rowA = pr, rowB = pr + 32;
  const bool x64 = (t < 8);       // pair 0 also handles row 64
  const int r0 = s0 + blockIdx.x * BBWD;
  int re = r0 + BBWD - 1 + WBWD; if (re > RTOT - 1) re = RTOT - 1;

  for (int i = t; i < 65*LSTR; i += 256) vw[i] = 0.0f;

  #define YPTR(RO_, S_) \
    ((S_) == 0  ? (gY0 + (size_t)(RO_)*32) : \
     (S_) <= 32 ? (gY1 + (size_t)(RO_)*1024 + (size_t)((S_)-1)*32) \
                : (gY2 + (size_t)(RO_)*1024 + (size_t)((S_)-33)*32))

  f32x4 z = {0,0,0,0};
  // prologue for r = re
  const int reo = re - s0;
  f32x4 pD = *(const f32x4*)&gD[(size_t)reo*1024 + t*4];
  f32x4 yA, yB, yC = z;
  yA = *(const f32x4*)&(YPTR(reo, rowA))[o*4];
  yB = *(const f32x4*)&(YPTR(reo, rowB))[o*4];
  if (x64) yC = *(const f32x4*)&(YPTR(reo, 64))[o*4];
  *(f32x4*)&Dl[re & 1][pr*LSTR + o*4] = pD;
  if (re > r0) pD = *(const f32x4*)&gD[(size_t)(reo-1)*1024 + t*4];
  __syncthreads();

  for (int r = re; r >= r0; --r) {
    const int cur = r & 1;
    const int ro = r - s0;

    // (1) stage D(r-1) from last iteration's prefetch register; safe: the
    // last reads of Dl[cur^1] were at iter r+1, before its ending barrier.
    if (r > r0) *(f32x4*)&Dl[cur ^ 1][pr*LSTR + o*4] = pD;
    // (2) issue next-iteration global loads NOW; the matmul below covers
    // their latency so the barrier's vmcnt(0) drain is cheap.
    f32x4 nyA = z, nyB = z, nyC = z;
    if (r - 1 > r0) pD = *(const f32x4*)&gD[(size_t)(ro-2)*1024 + t*4];
    if (r > r0) {
      nyA = *(const f32x4*)&(YPTR(ro - 1, rowA))[o*4];
      nyB = *(const f32x4*)&(YPTR(ro - 1, rowB))[o*4];
      if (x64) nyC = *(const f32x4*)&(YPTR(ro - 1, 64))[o*4];
    }

    // (3) matmul: load both vw rows into registers
    float vrA[32], vrB[32];
    #pragma unroll
    for (int c = 0; c < 8; ++c) {
      f32x4 qa = *(const f32x4*)&vw[rowA*LSTR + c*4];
      f32x4 qb = *(const f32x4*)&vw[rowB*LSTR + c*4];
      vrA[c*4+0]=qa[0]; vrA[c*4+1]=qa[1]; vrA[c*4+2]=qa[2]; vrA[c*4+3]=qa[3];
      vrB[c*4+0]=qb[0]; vrB[c*4+1]=qb[1]; vrB[c*4+2]=qb[2]; vrB[c*4+3]=qb[3];
    }

    float a0=yA[0],a1=yA[1],a2=yA[2],a3=yA[3];
    float b0=yB[0],b1=yB[1],b2=yB[2],b3=yB[3];
    #pragma unroll 4
    for (int k = 0; k < 32; ++k) {
      f32x4 d = *(const f32x4*)&Dl[cur][k*LSTR + o*4];
      float xa = vrA[k], xb = vrB[k];
      a0=fmaf(xa,d[0],a0); a1=fmaf(xa,d[1],a1);
      a2=fmaf(xa,d[2],a2); a3=fmaf(xa,d[3],a3);
      b0=fmaf(xb,d[0],b0); b1=fmaf(xb,d[1],b1);
      b2=fmaf(xb,d[2],b2); b3=fmaf(xb,d[3],b3);
    }
    f32x4 va = {a0,a1,a2,a3}, vb = {b0,b1,b2,b3};
    *(f32x4*)&vw[rowA*LSTR + o*4] = va;
    *(f32x4*)&vw[rowB*LSTR + o*4] = vb;

    // row 64 + v0 broadcast on pair 0 (masked; D re-read from LDS)
    float c0=0,c1=0,c2=0,c3=0;
    if (x64) {
      *(f32x4*)&v0buf[cur][o*4] = va;   // rowA == 0 here
      float vrC[32];
      #pragma unroll
      for (int c = 0; c < 8; ++c) {
        f32x4 q = *(const f32x4*)&vw[64*LSTR + c*4];
        vrC[c*4+0]=q[0]; vrC[c*4+1]=q[1]; vrC[c*4+2]=q[2]; vrC[c*4+3]=q[3];
      }
      c0=yC[0]; c1=yC[1]; c2=yC[2]; c3=yC[3];
      #pragma unroll 4
      for (int k = 0; k < 32; ++k) {
        f32x4 d = *(const f32x4*)&Dl[cur][k*LSTR + o*4];
        float xc = vrC[k];
        c0=fmaf(xc,d[0],c0); c1=fmaf(xc,d[1],c1);
        c2=fmaf(xc,d[2],c2); c3=fmaf(xc,d[3],c3);
      }
      f32x4 vc = {c0,c1,c2,c3};
      *(f32x4*)&vw[64*LSTR + o*4] = vc;
    }

    __syncthreads();

    if (r < r0 + BBWD) {
      f32x4 v0 = *(const f32x4*)&v0buf[cur][o*4];
      if (pr >= 1) {   // rowA -> out row pr-1
        float* dst = outg + ((size_t)r*64 + (size_t)(pr-1))*32 + o*4;
        f32x4 oo = {a0+v0[0], a1+v0[1], a2+v0[2], a3+v0[3]};
        *(f32x4*)dst = oo;
      }
      {                // rowB -> out row pr+31
        float* dst = outg + ((size_t)r*64 + (size_t)(pr+31))*32 + o*4;
        f32x4 oo = {b0+v0[0], b1+v0[1], b2+v0[2], b3+v0[3]};
        *(f32x4*)dst = oo;
      }
      if (x64) {       // row 64 -> out row 63
        float* dst = outg + ((size_t)r*64 + 63)*32 + o*4;
        f32x4 oo = {c0+v0[0], c1+v0[1], c2+v0[2], c3+v0[3]};
        *(f32x4*)dst = oo;
      }
    }

    yA = nyA; yB = nyB;
    if (x64) yC = nyC;
  }
  #undef YPTR
}

extern "C" void kernel_launch(void* const* d_in, const int* in_sizes, int n_in,
                              void* d_out, int out_size, void* d_ws, size_t ws_size,
                              hipStream_t stream) {
  (void)in_sizes; (void)n_in; (void)out_size;
  const void* H = d_in[0];   // x_hessian_diags [R,32,32]
  const void* G = d_in[1];   // x_grads         [R,1,32]
  const void* M = d_in[2];   // x_trans_mat     [32,32]
  const void* W = d_in[3];   // x_trans_prec    [32,32]
  const void* I = d_in[4];   // x_init_prec     [32,32]
  const void* E = d_in[5];   // epsx            [R,64,32]
  float* out = (float*)d_out;  // [R,64,32] fp32

  int* flag = (int*)d_ws;                         // dtype flag (first 256 B reserved)
  float* ws0 = (float*)((char*)d_ws + 256);
  size_t avail = (ws_size > 256) ? (ws_size - 256) : 0;

  // Per-row ws: Linv/Ye1 4KB + Ct/D 4KB + U/Y0 128B + Ye2 4KB = 12416 B.
  int nseg = 64;
  for (int cand = 1; cand <= 64; cand <<= 1) {
    size_t nrext = (size_t)(RTOT / cand) + WBWD;
    if (nrext * 12416 <= avail) { nseg = cand; break; }
  }
  const int segrows = RTOT / nseg;
  const size_t nrext_max = (size_t)segrows + WBWD;

  float* gLinv = ws0;                               // then Ye rows 0..31
  float* gCt  = ws0 + nrext_max * 1024;             // then D
  float* gU   = ws0 + nrext_max * 2048;             // then Y0
  float* gY2  = ws0 + nrext_max * 2080;             // Ye rows 32..63

  detect_kernel<<<1, 64, 0, stream>>>(W, flag);

  for (int s = 0; s < nseg; ++s) {
    int s0 = s * segrows;
    int s1ext = s0 + segrows + WBWD; if (s1ext > RTOT) s1ext = RTOT;
    int nr = s1ext - s0;
    int nfb = (nr + BFWD - 1) / BFWD;
    fwd_kernel<<<nfb, 64, 0, stream>>>(H, G, M, W, I, s0, flag, gLinv, gCt, gU);
    mid_kernel<<<nr, 256, 0, stream>>>(E, flag, gLinv, gCt, gU, gY2, s0);
    bwd_kernel<<<segrows / BBWD, 256, 0, stream>>>(gCt, gLinv, gY2, gU, out, s0);
  }
}